// Round 12
// baseline (554.269 us; speedup 1.0000x reference)
//
#include <hip/hip_runtime.h>
#include <cstddef>

// ---------------------------------------------------------------------------
// TransformerNet: 4-layer GATv2 GNN on MI355X (gfx950).
// R12: (1) gat_dst 2-edge unrolled pipeline (2-deep prefetch, 2 interleaved
// shfl/exp chains) — R11 left VALUBusy at 64% (latency leak at 1 gather/
// subgroup). (2) transposed gemm MFMA: C[dim][node] so each lane holds 4
// consecutive dims of one node -> 8B packed stores (R11 did 32x 2B scalar
// stores/lane). packB layout unchanged (it IS the A-layout of W^T).
// ---------------------------------------------------------------------------

typedef __attribute__((ext_vector_type(8))) short bf16x8;  // 8 bf16 = 4 VGPR
typedef __attribute__((ext_vector_type(4))) float f32x4;

#define NSH   10              // nodes-per-bucket shift (1024)
#define CHUNK 8192            // items per partition chunk
#define POOLP 256             // pool stage-1 blocks

__device__ __forceinline__ unsigned short f2bf(float f) {
  unsigned int u = __float_as_uint(f);
  u += 0x7fffu + ((u >> 16) & 1u);            // round-to-nearest-even
  return (unsigned short)(u >> 16);
}
__device__ __forceinline__ float bf2f(short s) {
  return __uint_as_float(((unsigned int)(unsigned short)s) << 16);
}
// pack two fp32 -> two bf16 (RTZ) in one dword: (hi(b)) | (a>>16)
__device__ __forceinline__ unsigned int pack2bf(float a, float b) {
  return (__float_as_uint(a) >> 16) | (__float_as_uint(b) & 0xFFFF0000u);
}
// unpack packed pair of bf16 (one uint32) -> float2 (1 VALU inst per element)
__device__ __forceinline__ float2 unpk(unsigned int u) {
  return make_float2(__uint_as_float(u << 16),
                     __uint_as_float(u & 0xFFFF0000u));
}

// exclusive scan of a[0..len) in LDS with 256 threads; a rewritten in place;
// returns total. aux = 256-int scratch. len <= 1024.
__device__ __forceinline__ int lds_excl_scan(int* a, int len, int* aux, int tid)
{
  int g = (len + 255) >> 8;                   // elements per thread
  int lo = tid * g;
  int s = 0;
  for (int i = 0; i < g; ++i) { int idx = lo + i; if (idx < len) s += a[idx]; }
  aux[tid] = s;
  __syncthreads();
  for (int d = 1; d < 256; d <<= 1) {
    int v = (tid >= d) ? aux[tid - d] : 0;
    __syncthreads();
    aux[tid] += v;
    __syncthreads();
  }
  int run = aux[tid] - s;                     // exclusive base of this span
  for (int i = 0; i < g; ++i) {
    int idx = lo + i;
    if (idx < len) { int t = a[idx]; a[idx] = run; run += t; }
  }
  int total = aux[255];
  __syncthreads();
  return total;
}

// resolve item id -> (layer, src, dst). Items = all edges then 4*n self-loops.
__device__ __forceinline__ void resolve_item(
    int id, int t1, int t2, int t3, int t4, int n,
    const int* s0, const int* s1, const int* s2, const int* s3,
    const int* d0, const int* d1, const int* d2, const int* d3,
    int& l, int& s, int& d, bool need_src)
{
  if (id < t4) {
    const int *sp, *dp; int e;
    if      (id < t1) { l = 0; e = id;      sp = s0; dp = d0; }
    else if (id < t2) { l = 1; e = id - t1; sp = s1; dp = d1; }
    else if (id < t3) { l = 2; e = id - t2; sp = s2; dp = d2; }
    else              { l = 3; e = id - t3; sp = s3; dp = d3; }
    d = dp[e];
    s = need_src ? sp[e] : 0;
  } else {
    int k = id - t4;
    l = (k >= 3 * n) ? 3 : (k >= 2 * n) ? 2 : (k >= n) ? 1 : 0;
    s = k - l * n; d = s;                     // self-loop
  }
}

// ------- setup: pack layer W + embed W + offs4 layer-end sentinels ---------
// packB[ct=16][kt=4][lane=64][j=8] per layer; element = W[k][col],
// k = kt*32 + (lane>>4)*8 + j, col = ct*16 + (lane&15); ct<8 -> Wl, else Wr.
// (This is simultaneously the A-operand layout of W^T — used as A in R12.)
__global__ __launch_bounds__(256) void setup_kernel(
    const float* __restrict__ Wl, const float* __restrict__ Wr,
    const float* __restrict__ embW,
    unsigned short* __restrict__ packB, unsigned short* __restrict__ packE,
    int* __restrict__ offs4, int n, int e0, int e1, int e2, int e3)
{
  int id = blockIdx.x * 256 + threadIdx.x;
  if (id < 131072) {
    int j    = id & 7;
    int lane = (id >> 3) & 63;
    int kt   = (id >> 9) & 3;
    int ct   = (id >> 11) & 15;
    int l    = id >> 15;
    int k    = kt * 32 + (lane >> 4) * 8 + j;
    int col  = ct * 16 + (lane & 15);
    float v = (ct < 8) ? Wl[(size_t)l * 16384 + k * 128 + col]
                       : Wr[(size_t)l * 16384 + k * 128 + (col - 128)];
    packB[id] = f2bf(v);
  }
  int pe = id - 131072;
  if (pe >= 0 && pe < 4096) {
    int j    = pe & 7;
    int lane = (pe >> 3) & 63;
    int ct   = pe >> 9;
    int k    = (lane >> 4) * 8 + j;
    int col  = ct * 16 + (lane & 15);
    packE[pe] = f2bf(embW[k * 128 + col]);
  }
  int q = pe - 4096;
  if (q >= 0 && q < 4) {
    int El = (q == 0) ? e0 : (q == 1) ? e1 : (q == 2) ? e2 : e3;
    offs4[(size_t)q * (n + 1) + n] = El + n;
  }
}

// ------- embed GEMM (MFMA): hb[n,128](bf16) = x[n,32] @ embW + b -----------
__global__ __launch_bounds__(256) void embed_mfma_kernel(
    const float* __restrict__ x, const unsigned short* __restrict__ packE,
    const float* __restrict__ b, unsigned short* __restrict__ hb, int n)
{
  const int wave = threadIdx.x >> 6;
  const int lane = threadIdx.x & 63;
  const int rlan = lane & 15;
  const int kgrp = lane >> 4;

  bf16x8 Bf[8];
#pragma unroll
  for (int ct = 0; ct < 8; ++ct)
    Bf[ct] = *(const bf16x8*)(packE + ((size_t)ct * 64 + lane) * 8);
  float bv[8];
#pragma unroll
  for (int ct = 0; ct < 8; ++ct) bv[ct] = b[ct * 16 + rlan];

  const float4* __restrict__ x4 = (const float4*)x;
  const int ntiles = (n + 15) / 16;
  for (int tile = blockIdx.x * 4 + wave; tile < ntiles; tile += gridDim.x * 4) {
    int r = tile * 16 + rlan;
    if (r >= n) r = n - 1;                    // clamp (writes are guarded)
    float4 a0 = x4[(size_t)r * 8 + kgrp * 2];
    float4 a1 = x4[(size_t)r * 8 + kgrp * 2 + 1];
    bf16x8 Af;
    Af[0] = (short)f2bf(a0.x); Af[1] = (short)f2bf(a0.y);
    Af[2] = (short)f2bf(a0.z); Af[3] = (short)f2bf(a0.w);
    Af[4] = (short)f2bf(a1.x); Af[5] = (short)f2bf(a1.y);
    Af[6] = (short)f2bf(a1.z); Af[7] = (short)f2bf(a1.w);

    f32x4 acc[8];
#pragma unroll
    for (int ct = 0; ct < 8; ++ct) {
      acc[ct] = (f32x4){0.f, 0.f, 0.f, 0.f};
      acc[ct] = __builtin_amdgcn_mfma_f32_16x16x32_bf16(Af, Bf[ct], acc[ct], 0, 0, 0);
    }
    // C/D: col = lane&15, row = kgrp*4 + reg
    int rowb = tile * 16 + kgrp * 4;
#pragma unroll
    for (int ct = 0; ct < 8; ++ct) {
      int col = ct * 16 + rlan;
#pragma unroll
      for (int rr = 0; rr < 4; ++rr)
        if (rowb + rr < n)
          hb[(size_t)(rowb + rr) * 128 + col] = f2bf(acc[ct][rr] + bv[ct]);
    }
  }
}

// ---- layer GEMM (MFMA, transposed): C[dim][node] = W^T(A) x h^T(B) --------
// Wave w: w<2 -> Wl dims (w&1)*64.., w>=2 -> Wr. A-frags = packB (64 VGPRs,
// resident). Per 16-node tile: 4 B-loads (h rows, 16B each), 16 MFMAs,
// epilogue: lane holds 4 consecutive dims of node (lane&15) -> 8B store.
__global__ __launch_bounds__(256) void gemm_mfma_kernel(
    const unsigned short* __restrict__ hb,
    const unsigned short* __restrict__ packB,   // this layer's [16][4][64][8]
    unsigned short* __restrict__ xlb, unsigned short* __restrict__ xrb, int n)
{
  const int wave = threadIdx.x >> 6;
  const int lane = threadIdx.x & 63;
  const int nlan = lane & 15;        // node within tile
  const int kgrp = lane >> 4;

  bf16x8 Af[4][4];                   // W^T A-frags: 4 dim-tiles x 4 k-tiles
#pragma unroll
  for (int mt = 0; mt < 4; ++mt)
#pragma unroll
    for (int kt = 0; kt < 4; ++kt)
      Af[mt][kt] = *(const bf16x8*)(packB +
          ((((size_t)(wave * 4 + mt)) * 4 + kt) * 64 + lane) * 8);

  unsigned short* __restrict__ outp = (wave < 2) ? xlb : xrb;  // wave-uniform
  const int dimbase = (wave & 1) * 64;

  const int ntiles = (n + 15) / 16;
  for (int tile = blockIdx.x; tile < ntiles; tile += gridDim.x) {
    int node = tile * 16 + nlan;
    int nc = (node < n) ? node : n - 1;       // clamp (stores guarded)
    const unsigned short* bp = hb + (size_t)nc * 128 + kgrp * 8;
    bf16x8 Bf[4];
#pragma unroll
    for (int kt = 0; kt < 4; ++kt)
      Bf[kt] = *(const bf16x8*)(bp + kt * 32);

    f32x4 acc[4];
#pragma unroll
    for (int mt = 0; mt < 4; ++mt)
      acc[mt] = (f32x4){0.f, 0.f, 0.f, 0.f};
#pragma unroll
    for (int kt = 0; kt < 4; ++kt)
#pragma unroll
      for (int mt = 0; mt < 4; ++mt)
        acc[mt] = __builtin_amdgcn_mfma_f32_16x16x32_bf16(
            Af[mt][kt], Bf[kt], acc[mt], 0, 0, 0);

    // C/D: col(lane&15) = node, row(kgrp*4+reg) = dim within tile
    if (node < n) {
      size_t rowbase = (size_t)node * 128 + dimbase + kgrp * 4;
#pragma unroll
      for (int mt = 0; mt < 4; ++mt) {
        uint2 pk;
        pk.x = pack2bf(acc[mt][0], acc[mt][1]);
        pk.y = pack2bf(acc[mt][2], acc[mt][3]);
        *(uint2*)(outp + rowbase + mt * 16) = pk;
      }
    }
  }
}

// ---------------- radix-partition CSR build --------------------------------
// Level 1a: per-chunk histogram over NB = 4*nbk global buckets.
__global__ __launch_bounds__(256) void hist_kernel(
    const int* __restrict__ d0, const int* __restrict__ d1,
    const int* __restrict__ d2, const int* __restrict__ d3,
    int e0, int e1, int e2, int e3, int n, int nbk, int NB, int nitems,
    int* __restrict__ mat)
{
  __shared__ int hist[512];
  int tid = threadIdx.x, c = blockIdx.x;
  for (int i = tid; i < NB; i += 256) hist[i] = 0;
  __syncthreads();
  int t1 = e0, t2 = t1 + e1, t3 = t2 + e2, t4 = t3 + e3;
  int base = c * CHUNK;
#pragma unroll
  for (int k = 0; k < CHUNK / 256; ++k) {
    int id = base + k * 256 + tid;
    if (id < nitems) {
      int l, s, d;
      resolve_item(id, t1, t2, t3, t4, n,
                   nullptr, nullptr, nullptr, nullptr, d0, d1, d2, d3,
                   l, s, d, false);
      atomicAdd(&hist[l * nbk + (d >> NSH)], 1);
    }
  }
  __syncthreads();
  for (int i = tid; i < NB; i += 256) mat[(size_t)c * NB + i] = hist[i];
}

// Level 1b: per-bucket column scan of mat -> pfx (mat counts preserved),
// emits column totals.
__global__ __launch_bounds__(256) void colscan_a_kernel(
    const int* __restrict__ mat, int* __restrict__ pfx,
    int nchunk, int NB, int* __restrict__ colsum)
{
  __shared__ int col[512];
  __shared__ int aux[256];
  int gb = blockIdx.x, tid = threadIdx.x;
  for (int i = tid; i < nchunk; i += 256) col[i] = mat[(size_t)i * NB + gb];
  __syncthreads();
  int tot = lds_excl_scan(col, nchunk, aux, tid);
  for (int i = tid; i < nchunk; i += 256) pfx[(size_t)i * NB + gb] = col[i];
  if (tid == 0) colsum[gb] = tot;
}

__global__ __launch_bounds__(256) void colscan_b_kernel(
    const int* __restrict__ colsum, int NB, int* __restrict__ colscan)
{
  __shared__ int buf[512];
  __shared__ int aux[256];
  int tid = threadIdx.x;
  for (int i = tid; i < NB; i += 256) buf[i] = colsum[i];
  __syncthreads();
  int tot = lds_excl_scan(buf, NB, aux, tid);
  for (int i = tid; i < NB; i += 256) colscan[i] = buf[i];
  if (tid == 0) colscan[NB] = tot;
}

// Level 1c: scatter chunk items into bucket-major staging via LDS reorder.
__global__ __launch_bounds__(256) void scatter_kernel(
    const int* __restrict__ s0, const int* __restrict__ s1,
    const int* __restrict__ s2, const int* __restrict__ s3,
    const int* __restrict__ d0, const int* __restrict__ d1,
    const int* __restrict__ d2, const int* __restrict__ d3,
    int e0, int e1, int e2, int e3, int n, int nbk, int NB, int nitems,
    const int* __restrict__ mat, const int* __restrict__ pfx,
    const int* __restrict__ colscan, int* __restrict__ staging)
{
  __shared__ int lbuf[CHUNK];
  __shared__ int hist[512];    // within-chunk exclusive offsets
  __shared__ int cur[512];
  __shared__ int basex[512];
  __shared__ int aux[256];
  int tid = threadIdx.x, c = blockIdx.x;
  for (int i = tid; i < NB; i += 256) hist[i] = mat[(size_t)c * NB + i];
  __syncthreads();
  lds_excl_scan(hist, NB, aux, tid);
  for (int i = tid; i < NB; i += 256) {
    cur[i]   = hist[i];
    basex[i] = colscan[i] + pfx[(size_t)c * NB + i];
  }
  __syncthreads();
  int t1 = e0, t2 = t1 + e1, t3 = t2 + e2, t4 = t3 + e3;
  int base = c * CHUNK;
#pragma unroll
  for (int k = 0; k < CHUNK / 256; ++k) {
    int id = base + k * 256 + tid;
    if (id < nitems) {
      int l, s, d;
      resolve_item(id, t1, t2, t3, t4, n,
                   s0, s1, s2, s3, d0, d1, d2, d3, l, s, d, true);
      int gb = l * nbk + (d >> NSH);
      int p = atomicAdd(&cur[gb], 1);
      lbuf[p] = s | ((d & ((1 << NSH) - 1)) << 17);
    }
  }
  __syncthreads();
  // write out bucket runs (contiguous per bucket; coalesced within run)
  int wave = tid >> 6, lane = tid & 63;
  for (int gb = wave; gb < NB; gb += 4) {
    int st = hist[gb], en = cur[gb];
    int gbase = basex[gb];
    for (int j = lane; j < en - st; j += 64)
      staging[gbase + j] = lbuf[st + j];
  }
}

// Level 2: one block per (layer,bucket): node-level counting sort of the
// bucket's contiguous slice -> offs + final csr (block-local write window).
__global__ __launch_bounds__(256) void finalize_kernel(
    const int* __restrict__ staging, const int* __restrict__ colscan,
    int* __restrict__ offs4, int* __restrict__ csr4, int n, int nbk,
    int cb0, int cb1, int cb2, int cb3)
{
  __shared__ int cnt[1 << NSH];
  __shared__ int pos[1 << NSH];
  __shared__ int aux[256];
  int gb = blockIdx.x, tid = threadIdx.x;
  int l = gb / nbk, b = gb % nbk;
  int beg = colscan[gb], end = colscan[gb + 1];
  int node0 = b << NSH;
  int ncount = n - node0; if (ncount > (1 << NSH)) ncount = 1 << NSH;
  int cbl = (l == 0) ? cb0 : (l == 1) ? cb1 : (l == 2) ? cb2 : cb3;

  for (int i = tid; i < (1 << NSH); i += 256) cnt[i] = 0;
  __syncthreads();
  for (int t = beg + tid; t < end; t += 256)
    atomicAdd(&cnt[staging[t] >> 17], 1);
  __syncthreads();
  lds_excl_scan(cnt, 1 << NSH, aux, tid);
  for (int i = tid; i < (1 << NSH); i += 256) {
    if (i < ncount)
      offs4[(size_t)l * (n + 1) + node0 + i] = beg + cnt[i] - cbl;
    pos[i] = cnt[i];
  }
  __syncthreads();
  for (int t = beg + tid; t < end; t += 256) {
    int e = staging[t];
    int p = atomicAdd(&pos[e >> 17], 1);
    csr4[beg + p] = e & 0x1FFFF;
  }
}

// ---------------- fused GATv2 edge phase -----------------------------------
// SUBGROUP-PER-NODE: 16 lanes own one dst node (4 nodes/wave). 2 edges per
// iteration with 2-deep prefetch (2 outstanding gathers/subgroup, two
// interleaved shfl/exp chains). exp2 domain (att pre-scaled by log2e).
__global__ __launch_bounds__(256) void gat_dst_kernel(
    const unsigned short* __restrict__ xlb,
    const unsigned short* __restrict__ xrb,
    const int* __restrict__ offs, const int* __restrict__ csr,
    const float* __restrict__ att, const float* __restrict__ bias,
    float* __restrict__ hout_f, unsigned short* __restrict__ hout_b, int n)
{
  const float LOG2E = 1.4426950408889634f;
  int wid = (blockIdx.x * 256 + threadIdx.x) >> 4;   // subgroup id = node
  int c   = threadIdx.x & 15;                        // dim chunk c*8..c*8+7
  if (wid >= n) return;

  uint4 xru = *(const uint4*)(xrb + (size_t)wid * 128 + c * 8);
  float2 xr0 = unpk(xru.x), xr1 = unpk(xru.y);
  float2 xr2 = unpk(xru.z), xr3 = unpk(xru.w);
  const float2* att2 = (const float2*)att + c * 4;
  float2 a0 = att2[0], a1 = att2[1], a2 = att2[2], a3 = att2[3];
  a0.x *= LOG2E; a0.y *= LOG2E; a1.x *= LOG2E; a1.y *= LOG2E;
  a2.x *= LOG2E; a2.y *= LOG2E; a3.x *= LOG2E; a3.y *= LOG2E;

  int beg = offs[wid], end = offs[wid + 1];
  float ssum = 0.f;
  float2 ac0 = {0.f, 0.f}, ac1 = {0.f, 0.f};
  float2 ac2 = {0.f, 0.f}, ac3 = {0.f, 0.f};

  // 2-deep prologue prefetch (deg >= 1 always)
  uint4 xu0 = *(const uint4*)(xlb + (size_t)csr[beg] * 128 + c * 8);
  uint4 xu1 = {0, 0, 0, 0};
  if (beg + 1 < end)
    xu1 = *(const uint4*)(xlb + (size_t)csr[beg + 1] * 128 + c * 8);

  for (int j = beg; j < end; j += 2) {
    uint4 cu0 = xu0, cu1 = xu1;
    bool act1 = (j + 1 < end);
    if (j + 2 < end)
      xu0 = *(const uint4*)(xlb + (size_t)csr[j + 2] * 128 + c * 8);
    if (j + 3 < end)
      xu1 = *(const uint4*)(xlb + (size_t)csr[j + 3] * 128 + c * 8);

    // edge 0 (always valid)
    float2 e0s0 = unpk(cu0.x), e0s1 = unpk(cu0.y);
    float2 e0s2 = unpk(cu0.z), e0s3 = unpk(cu0.w);
    // edge 1 (predicated by act1)
    float2 e1s0 = unpk(cu1.x), e1s1 = unpk(cu1.y);
    float2 e1s2 = unpk(cu1.z), e1s3 = unpk(cu1.w);

    float2 t00 = {e0s0.x + xr0.x, e0s0.y + xr0.y};
    float2 t01 = {e0s1.x + xr1.x, e0s1.y + xr1.y};
    float2 t02 = {e0s2.x + xr2.x, e0s2.y + xr2.y};
    float2 t03 = {e0s3.x + xr3.x, e0s3.y + xr3.y};
    float2 t10 = {e1s0.x + xr0.x, e1s0.y + xr0.y};
    float2 t11 = {e1s1.x + xr1.x, e1s1.y + xr1.y};
    float2 t12 = {e1s2.x + xr2.x, e1s2.y + xr2.y};
    float2 t13 = {e1s3.x + xr3.x, e1s3.y + xr3.y};
    t00.x = fmaxf(t00.x, 0.2f * t00.x); t00.y = fmaxf(t00.y, 0.2f * t00.y);
    t01.x = fmaxf(t01.x, 0.2f * t01.x); t01.y = fmaxf(t01.y, 0.2f * t01.y);
    t02.x = fmaxf(t02.x, 0.2f * t02.x); t02.y = fmaxf(t02.y, 0.2f * t02.y);
    t03.x = fmaxf(t03.x, 0.2f * t03.x); t03.y = fmaxf(t03.y, 0.2f * t03.y);
    t10.x = fmaxf(t10.x, 0.2f * t10.x); t10.y = fmaxf(t10.y, 0.2f * t10.y);
    t11.x = fmaxf(t11.x, 0.2f * t11.x); t11.y = fmaxf(t11.y, 0.2f * t11.y);
    t12.x = fmaxf(t12.x, 0.2f * t12.x); t12.y = fmaxf(t12.y, 0.2f * t12.y);
    t13.x = fmaxf(t13.x, 0.2f * t13.x); t13.y = fmaxf(t13.y, 0.2f * t13.y);

    float2 p0 = {t00.x * a0.x, t00.y * a0.y};
    p0.x = fmaf(t01.x, a1.x, p0.x); p0.y = fmaf(t01.y, a1.y, p0.y);
    p0.x = fmaf(t02.x, a2.x, p0.x); p0.y = fmaf(t02.y, a2.y, p0.y);
    p0.x = fmaf(t03.x, a3.x, p0.x); p0.y = fmaf(t03.y, a3.y, p0.y);
    float2 p1 = {t10.x * a0.x, t10.y * a0.y};
    p1.x = fmaf(t11.x, a1.x, p1.x); p1.y = fmaf(t11.y, a1.y, p1.y);
    p1.x = fmaf(t12.x, a2.x, p1.x); p1.y = fmaf(t12.y, a2.y, p1.y);
    p1.x = fmaf(t13.x, a3.x, p1.x); p1.y = fmaf(t13.y, a3.y, p1.y);

    float part0 = p0.x + p0.y;
    float part1 = p1.x + p1.y;
    part0 += __shfl_xor(part0, 1, 64);   part1 += __shfl_xor(part1, 1, 64);
    part0 += __shfl_xor(part0, 2, 64);   part1 += __shfl_xor(part1, 2, 64);
    part0 += __shfl_xor(part0, 4, 64);   part1 += __shfl_xor(part1, 4, 64);
    part0 += __shfl_xor(part0, 8, 64);   part1 += __shfl_xor(part1, 8, 64);
    float pe0 = __builtin_amdgcn_exp2f(part0);
    float pe1 = act1 ? __builtin_amdgcn_exp2f(part1) : 0.f;
    ssum += pe0 + pe1;
    ac0.x = fmaf(pe0, e0s0.x, ac0.x); ac0.y = fmaf(pe0, e0s0.y, ac0.y);
    ac1.x = fmaf(pe0, e0s1.x, ac1.x); ac1.y = fmaf(pe0, e0s1.y, ac1.y);
    ac2.x = fmaf(pe0, e0s2.x, ac2.x); ac2.y = fmaf(pe0, e0s2.y, ac2.y);
    ac3.x = fmaf(pe0, e0s3.x, ac3.x); ac3.y = fmaf(pe0, e0s3.y, ac3.y);
    ac0.x = fmaf(pe1, e1s0.x, ac0.x); ac0.y = fmaf(pe1, e1s0.y, ac0.y);
    ac1.x = fmaf(pe1, e1s1.x, ac1.x); ac1.y = fmaf(pe1, e1s1.y, ac1.y);
    ac2.x = fmaf(pe1, e1s2.x, ac2.x); ac2.y = fmaf(pe1, e1s2.y, ac2.y);
    ac3.x = fmaf(pe1, e1s3.x, ac3.x); ac3.y = fmaf(pe1, e1s3.y, ac3.y);
  }

  float inv = 1.0f / ssum;
  float o[8] = {ac0.x, ac0.y, ac1.x, ac1.y, ac2.x, ac2.y, ac3.x, ac3.y};
#pragma unroll
  for (int k = 0; k < 8; ++k) o[k] = fmaf(o[k], inv, bias[c * 8 + k]);

  if (hout_f) {
    float4 v0 = make_float4(o[0], o[1], o[2], o[3]);
    float4 v1 = make_float4(o[4], o[5], o[6], o[7]);
    *(float4*)(hout_f + (size_t)wid * 128 + c * 8)     = v0;
    *(float4*)(hout_f + (size_t)wid * 128 + c * 8 + 4) = v1;
  } else {
    bf16x8 ob;
#pragma unroll
    for (int k = 0; k < 8; ++k) ob[k] = (short)f2bf(o[k]);
    *(bf16x8*)(hout_b + (size_t)wid * 128 + c * 8) = ob;
  }
}

// ---------------- two-stage pooling + fused reduce+output GEMM -------------
__global__ __launch_bounds__(256) void pool_partial_kernel(
    const float* __restrict__ h, const int* __restrict__ gnode,
    const int* __restrict__ bidx, float* __restrict__ partial, int ng)
{
  __shared__ float acc[64 * 128];           // 32 KiB
  int tid = threadIdx.x;
  for (int t = tid; t < 64 * 128; t += 256) acc[t] = 0.f;
  __syncthreads();
  int col = tid & 127, half = tid >> 7;
  for (int nd = blockIdx.x * 2 + half; nd < ng; nd += gridDim.x * 2) {
    int row = gnode[nd];
    int g   = bidx[nd];
    atomicAdd(&acc[g * 128 + col], h[(size_t)row * 128 + col]);
  }
  __syncthreads();
  float* out = partial + (size_t)blockIdx.x * 8192;
  for (int t = tid; t < 64 * 128; t += 256) out[t] = acc[t];
}

// one block per graph g: reduce partials for row g, then out[g] = pooled@W+b
__global__ __launch_bounds__(128) void pool_out_kernel(
    const float* __restrict__ partial, const float* __restrict__ W,
    const float* __restrict__ b, float* __restrict__ out)
{
  __shared__ float pr[128];
  int g = blockIdx.x, tid = threadIdx.x;    // tid = col
  float s = 0.f;
  for (int p = 0; p < POOLP; ++p) s += partial[(size_t)p * 8192 + g * 128 + tid];
  pr[tid] = s;
  __syncthreads();
  if (tid < 16) {
    float acc = b[tid];
#pragma unroll
    for (int k = 0; k < 128; ++k) acc += pr[k] * W[k * 16 + tid];
    out[g * 16 + tid] = acc;
  }
}

// ---------------------------------------------------------------------------
extern "C" void kernel_launch(void* const* d_in, const int* in_sizes, int n_in,
                              void* d_out, int out_size, void* d_ws, size_t ws_size,
                              hipStream_t stream)
{
  const float* x    = (const float*)d_in[0];
  const int* ei0    = (const int*)d_in[1];   // edge_index            [2,1e6]
  const int* ei_sg  = (const int*)d_in[2];   // subgraph_edge_index   [2,1e6]
  const int* ei_ns  = (const int*)d_in[3];   // node_subnode_index    [2,2e5]
  const int* ei_sn  = (const int*)d_in[4];   // subnode_node_index    [2,2e5]
  const int* gnode  = (const int*)d_in[5];   // ground_node
  // d_in[6] = subgraph_batch_index (unused by reference)
  const int* bidx   = (const int*)d_in[7];   // batch_idx
  const float* embW = (const float*)d_in[8];
  const float* embB = (const float*)d_in[9];
  const float* Wl   = (const float*)d_in[10];
  const float* Wr   = (const float*)d_in[11];
  const float* att  = (const float*)d_in[12];
  const float* bias = (const float*)d_in[13];
  const float* outW = (const float*)d_in[14];
  const float* outB = (const float*)d_in[15];

  const int n  = in_sizes[0] / 32;           // 100000
  const int ng = in_sizes[5];                // 40000

  // reference layer order: edge_index, node_subnode, subgraph_edge, subnode_node
  const int  E_arr[4] = { in_sizes[1] / 2, in_sizes[3] / 2,
                          in_sizes[2] / 2, in_sizes[4] / 2 };
  const int* eptr[4]  = { ei0, ei_ns, ei_sg, ei_sn };
  const int E_tot  = E_arr[0] + E_arr[1] + E_arr[2] + E_arr[3];
  const int nitems = E_tot + 4 * n;
  const int nbk    = (n + (1 << NSH) - 1) >> NSH;   // buckets per layer (98)
  const int NB     = 4 * nbk;                       // global buckets (392)
  const int nchunk = (nitems + CHUNK - 1) / CHUNK;  // 342
  // per-layer bases into csr/staging (layer l slice: E_l + n items)
  int cb[4];
  cb[0] = 0;
  for (int i = 1; i < 4; ++i) cb[i] = cb[i - 1] + E_arr[i - 1] + n;

  // workspace carve (bump allocator, 256B aligned)
  char* ws = (char*)d_ws;
  size_t off = 0;
  auto alloc = [&](size_t bytes) -> void* {
    void* p = ws + off;
    off = (off + bytes + 255) & ~(size_t)255;
    return p;
  };
  float*          h      = (float*)alloc((size_t)n * 128 * sizeof(float));
  unsigned short* hb     = (unsigned short*)alloc((size_t)n * 128 * sizeof(unsigned short));
  unsigned short* xlb    = (unsigned short*)alloc((size_t)n * 128 * sizeof(unsigned short));
  unsigned short* xrb    = (unsigned short*)alloc((size_t)n * 128 * sizeof(unsigned short));
  int*            offs4  = (int*)alloc((size_t)4 * (n + 1) * sizeof(int));
  int*            mat    = (int*)alloc((size_t)nchunk * NB * sizeof(int));
  int*            pfx    = (int*)alloc((size_t)nchunk * NB * sizeof(int));
  int*            colsum = (int*)alloc((size_t)NB * sizeof(int));
  int*            colscan= (int*)alloc((size_t)(NB + 1) * sizeof(int));
  int*            staging= (int*)alloc((size_t)nitems * sizeof(int));
  int*            csr4   = (int*)alloc((size_t)nitems * sizeof(int));
  unsigned short* packB  = (unsigned short*)alloc(131072 * sizeof(unsigned short));
  unsigned short* packE  = (unsigned short*)alloc(4096 * sizeof(unsigned short));
  float*          partial= (float*)alloc((size_t)POOLP * 8192 * sizeof(float));
  (void)ws_size; (void)n_in; (void)out_size;

  // dst rows of each edge list
  const int* D[4] = { eptr[0] + E_arr[0], eptr[1] + E_arr[1],
                      eptr[2] + E_arr[2], eptr[3] + E_arr[3] };

  int setup_items = 131072 + 4096 + 4;
  setup_kernel<<<(setup_items + 255) / 256, 256, 0, stream>>>(
      Wl, Wr, embW, packB, packE, offs4, n,
      E_arr[0], E_arr[1], E_arr[2], E_arr[3]);

  const int ntile16 = (n + 15) / 16;
  embed_mfma_kernel<<<(ntile16 + 3) / 4, 256, 0, stream>>>(
      x, packE, embB, hb, n);

  // atomic-free radix-partition CSR build (all 4 graphs)
  hist_kernel<<<nchunk, 256, 0, stream>>>(
      D[0], D[1], D[2], D[3], E_arr[0], E_arr[1], E_arr[2], E_arr[3],
      n, nbk, NB, nitems, mat);
  colscan_a_kernel<<<NB, 256, 0, stream>>>(mat, pfx, nchunk, NB, colsum);
  colscan_b_kernel<<<1, 256, 0, stream>>>(colsum, NB, colscan);
  scatter_kernel<<<nchunk, 256, 0, stream>>>(
      eptr[0], eptr[1], eptr[2], eptr[3], D[0], D[1], D[2], D[3],
      E_arr[0], E_arr[1], E_arr[2], E_arr[3], n, nbk, NB, nitems,
      mat, pfx, colscan, staging);
  finalize_kernel<<<NB, 256, 0, stream>>>(
      staging, colscan, offs4, csr4, n, nbk, cb[0], cb[1], cb[2], cb[3]);

  const int gemm_grid = (ntile16 + 1) / 2;          // 2 node-tiles per block
  for (int l = 0; l < 4; ++l) {
    gemm_mfma_kernel<<<gemm_grid, 256, 0, stream>>>(
        hb, packB + (size_t)l * 32768, xlb, xrb, n);
    gat_dst_kernel<<<((size_t)n * 16 + 255) / 256, 256, 0, stream>>>(
        xlb, xrb, offs4 + (size_t)l * (n + 1), csr4 + cb[l],
        att + (size_t)l * 128, bias + (size_t)l * 128,
        (l == 3) ? h : nullptr, (l < 3) ? hb : nullptr, n);
  }

  pool_partial_kernel<<<POOLP, 256, 0, stream>>>(h, gnode, bidx, partial, ng);
  pool_out_kernel<<<64, 128, 0, stream>>>(partial, outW, outB, (float*)d_out);
}

// Round 13
// 539.525 us; speedup vs baseline: 1.0273x; 1.0273x over previous
//
#include <hip/hip_runtime.h>
#include <cstddef>

// ---------------------------------------------------------------------------
// TransformerNet: 4-layer GATv2 GNN on MI355X (gfx950).
// R13: revert gat_dst to R11 exactly (R12's 2-edge unroll cost VGPR 32->44,
// occupancy 60->41%, +7.6us — per-thread ILP trades against occupancy and
// loses here, same as R10). Keep R12's transposed gemm as the only delta vs
// the R11 baseline (512us) for clean attribution of its effect.
// ---------------------------------------------------------------------------

typedef __attribute__((ext_vector_type(8))) short bf16x8;  // 8 bf16 = 4 VGPR
typedef __attribute__((ext_vector_type(4))) float f32x4;

#define NSH   10              // nodes-per-bucket shift (1024)
#define CHUNK 8192            // items per partition chunk
#define POOLP 256             // pool stage-1 blocks

__device__ __forceinline__ unsigned short f2bf(float f) {
  unsigned int u = __float_as_uint(f);
  u += 0x7fffu + ((u >> 16) & 1u);            // round-to-nearest-even
  return (unsigned short)(u >> 16);
}
__device__ __forceinline__ float bf2f(short s) {
  return __uint_as_float(((unsigned int)(unsigned short)s) << 16);
}
// pack two fp32 -> two bf16 (RTZ) in one dword: (hi(b)) | (a>>16)
__device__ __forceinline__ unsigned int pack2bf(float a, float b) {
  return (__float_as_uint(a) >> 16) | (__float_as_uint(b) & 0xFFFF0000u);
}
// unpack packed pair of bf16 (one uint32) -> float2 (1 VALU inst per element)
__device__ __forceinline__ float2 unpk(unsigned int u) {
  return make_float2(__uint_as_float(u << 16),
                     __uint_as_float(u & 0xFFFF0000u));
}

// exclusive scan of a[0..len) in LDS with 256 threads; a rewritten in place;
// returns total. aux = 256-int scratch. len <= 1024.
__device__ __forceinline__ int lds_excl_scan(int* a, int len, int* aux, int tid)
{
  int g = (len + 255) >> 8;                   // elements per thread
  int lo = tid * g;
  int s = 0;
  for (int i = 0; i < g; ++i) { int idx = lo + i; if (idx < len) s += a[idx]; }
  aux[tid] = s;
  __syncthreads();
  for (int d = 1; d < 256; d <<= 1) {
    int v = (tid >= d) ? aux[tid - d] : 0;
    __syncthreads();
    aux[tid] += v;
    __syncthreads();
  }
  int run = aux[tid] - s;                     // exclusive base of this span
  for (int i = 0; i < g; ++i) {
    int idx = lo + i;
    if (idx < len) { int t = a[idx]; a[idx] = run; run += t; }
  }
  int total = aux[255];
  __syncthreads();
  return total;
}

// resolve item id -> (layer, src, dst). Items = all edges then 4*n self-loops.
__device__ __forceinline__ void resolve_item(
    int id, int t1, int t2, int t3, int t4, int n,
    const int* s0, const int* s1, const int* s2, const int* s3,
    const int* d0, const int* d1, const int* d2, const int* d3,
    int& l, int& s, int& d, bool need_src)
{
  if (id < t4) {
    const int *sp, *dp; int e;
    if      (id < t1) { l = 0; e = id;      sp = s0; dp = d0; }
    else if (id < t2) { l = 1; e = id - t1; sp = s1; dp = d1; }
    else if (id < t3) { l = 2; e = id - t2; sp = s2; dp = d2; }
    else              { l = 3; e = id - t3; sp = s3; dp = d3; }
    d = dp[e];
    s = need_src ? sp[e] : 0;
  } else {
    int k = id - t4;
    l = (k >= 3 * n) ? 3 : (k >= 2 * n) ? 2 : (k >= n) ? 1 : 0;
    s = k - l * n; d = s;                     // self-loop
  }
}

// ------- setup: pack layer W + embed W + offs4 layer-end sentinels ---------
// packB[ct=16][kt=4][lane=64][j=8] per layer; element = W[k][col],
// k = kt*32 + (lane>>4)*8 + j, col = ct*16 + (lane&15); ct<8 -> Wl, else Wr.
// (This is simultaneously the A-operand layout of W^T — used as A in gemm.)
__global__ __launch_bounds__(256) void setup_kernel(
    const float* __restrict__ Wl, const float* __restrict__ Wr,
    const float* __restrict__ embW,
    unsigned short* __restrict__ packB, unsigned short* __restrict__ packE,
    int* __restrict__ offs4, int n, int e0, int e1, int e2, int e3)
{
  int id = blockIdx.x * 256 + threadIdx.x;
  if (id < 131072) {
    int j    = id & 7;
    int lane = (id >> 3) & 63;
    int kt   = (id >> 9) & 3;
    int ct   = (id >> 11) & 15;
    int l    = id >> 15;
    int k    = kt * 32 + (lane >> 4) * 8 + j;
    int col  = ct * 16 + (lane & 15);
    float v = (ct < 8) ? Wl[(size_t)l * 16384 + k * 128 + col]
                       : Wr[(size_t)l * 16384 + k * 128 + (col - 128)];
    packB[id] = f2bf(v);
  }
  int pe = id - 131072;
  if (pe >= 0 && pe < 4096) {
    int j    = pe & 7;
    int lane = (pe >> 3) & 63;
    int ct   = pe >> 9;
    int k    = (lane >> 4) * 8 + j;
    int col  = ct * 16 + (lane & 15);
    packE[pe] = f2bf(embW[k * 128 + col]);
  }
  int q = pe - 4096;
  if (q >= 0 && q < 4) {
    int El = (q == 0) ? e0 : (q == 1) ? e1 : (q == 2) ? e2 : e3;
    offs4[(size_t)q * (n + 1) + n] = El + n;
  }
}

// ------- embed GEMM (MFMA): hb[n,128](bf16) = x[n,32] @ embW + b -----------
__global__ __launch_bounds__(256) void embed_mfma_kernel(
    const float* __restrict__ x, const unsigned short* __restrict__ packE,
    const float* __restrict__ b, unsigned short* __restrict__ hb, int n)
{
  const int wave = threadIdx.x >> 6;
  const int lane = threadIdx.x & 63;
  const int rlan = lane & 15;
  const int kgrp = lane >> 4;

  bf16x8 Bf[8];
#pragma unroll
  for (int ct = 0; ct < 8; ++ct)
    Bf[ct] = *(const bf16x8*)(packE + ((size_t)ct * 64 + lane) * 8);
  float bv[8];
#pragma unroll
  for (int ct = 0; ct < 8; ++ct) bv[ct] = b[ct * 16 + rlan];

  const float4* __restrict__ x4 = (const float4*)x;
  const int ntiles = (n + 15) / 16;
  for (int tile = blockIdx.x * 4 + wave; tile < ntiles; tile += gridDim.x * 4) {
    int r = tile * 16 + rlan;
    if (r >= n) r = n - 1;                    // clamp (writes are guarded)
    float4 a0 = x4[(size_t)r * 8 + kgrp * 2];
    float4 a1 = x4[(size_t)r * 8 + kgrp * 2 + 1];
    bf16x8 Af;
    Af[0] = (short)f2bf(a0.x); Af[1] = (short)f2bf(a0.y);
    Af[2] = (short)f2bf(a0.z); Af[3] = (short)f2bf(a0.w);
    Af[4] = (short)f2bf(a1.x); Af[5] = (short)f2bf(a1.y);
    Af[6] = (short)f2bf(a1.z); Af[7] = (short)f2bf(a1.w);

    f32x4 acc[8];
#pragma unroll
    for (int ct = 0; ct < 8; ++ct) {
      acc[ct] = (f32x4){0.f, 0.f, 0.f, 0.f};
      acc[ct] = __builtin_amdgcn_mfma_f32_16x16x32_bf16(Af, Bf[ct], acc[ct], 0, 0, 0);
    }
    // C/D: col = lane&15, row = kgrp*4 + reg
    int rowb = tile * 16 + kgrp * 4;
#pragma unroll
    for (int ct = 0; ct < 8; ++ct) {
      int col = ct * 16 + rlan;
#pragma unroll
      for (int rr = 0; rr < 4; ++rr)
        if (rowb + rr < n)
          hb[(size_t)(rowb + rr) * 128 + col] = f2bf(acc[ct][rr] + bv[ct]);
    }
  }
}

// ---- layer GEMM (MFMA, transposed): C[dim][node] = W^T(A) x h^T(B) --------
// Wave w: w<2 -> Wl dims (w&1)*64.., w>=2 -> Wr. A-frags = packB (64 VGPRs,
// resident). Per 16-node tile: 4 B-loads (h rows, 16B each), 16 MFMAs,
// epilogue: lane holds 4 consecutive dims of node (lane&15) -> 8B store.
__global__ __launch_bounds__(256) void gemm_mfma_kernel(
    const unsigned short* __restrict__ hb,
    const unsigned short* __restrict__ packB,   // this layer's [16][4][64][8]
    unsigned short* __restrict__ xlb, unsigned short* __restrict__ xrb, int n)
{
  const int wave = threadIdx.x >> 6;
  const int lane = threadIdx.x & 63;
  const int nlan = lane & 15;        // node within tile
  const int kgrp = lane >> 4;

  bf16x8 Af[4][4];                   // W^T A-frags: 4 dim-tiles x 4 k-tiles
#pragma unroll
  for (int mt = 0; mt < 4; ++mt)
#pragma unroll
    for (int kt = 0; kt < 4; ++kt)
      Af[mt][kt] = *(const bf16x8*)(packB +
          ((((size_t)(wave * 4 + mt)) * 4 + kt) * 64 + lane) * 8);

  unsigned short* __restrict__ outp = (wave < 2) ? xlb : xrb;  // wave-uniform
  const int dimbase = (wave & 1) * 64;

  const int ntiles = (n + 15) / 16;
  for (int tile = blockIdx.x; tile < ntiles; tile += gridDim.x) {
    int node = tile * 16 + nlan;
    int nc = (node < n) ? node : n - 1;       // clamp (stores guarded)
    const unsigned short* bp = hb + (size_t)nc * 128 + kgrp * 8;
    bf16x8 Bf[4];
#pragma unroll
    for (int kt = 0; kt < 4; ++kt)
      Bf[kt] = *(const bf16x8*)(bp + kt * 32);

    f32x4 acc[4];
#pragma unroll
    for (int mt = 0; mt < 4; ++mt)
      acc[mt] = (f32x4){0.f, 0.f, 0.f, 0.f};
#pragma unroll
    for (int kt = 0; kt < 4; ++kt)
#pragma unroll
      for (int mt = 0; mt < 4; ++mt)
        acc[mt] = __builtin_amdgcn_mfma_f32_16x16x32_bf16(
            Af[mt][kt], Bf[kt], acc[mt], 0, 0, 0);

    // C/D: col(lane&15) = node, row(kgrp*4+reg) = dim within tile
    if (node < n) {
      size_t rowbase = (size_t)node * 128 + dimbase + kgrp * 4;
#pragma unroll
      for (int mt = 0; mt < 4; ++mt) {
        uint2 pk;
        pk.x = pack2bf(acc[mt][0], acc[mt][1]);
        pk.y = pack2bf(acc[mt][2], acc[mt][3]);
        *(uint2*)(outp + rowbase + mt * 16) = pk;
      }
    }
  }
}

// ---------------- radix-partition CSR build --------------------------------
// Level 1a: per-chunk histogram over NB = 4*nbk global buckets.
__global__ __launch_bounds__(256) void hist_kernel(
    const int* __restrict__ d0, const int* __restrict__ d1,
    const int* __restrict__ d2, const int* __restrict__ d3,
    int e0, int e1, int e2, int e3, int n, int nbk, int NB, int nitems,
    int* __restrict__ mat)
{
  __shared__ int hist[512];
  int tid = threadIdx.x, c = blockIdx.x;
  for (int i = tid; i < NB; i += 256) hist[i] = 0;
  __syncthreads();
  int t1 = e0, t2 = t1 + e1, t3 = t2 + e2, t4 = t3 + e3;
  int base = c * CHUNK;
#pragma unroll
  for (int k = 0; k < CHUNK / 256; ++k) {
    int id = base + k * 256 + tid;
    if (id < nitems) {
      int l, s, d;
      resolve_item(id, t1, t2, t3, t4, n,
                   nullptr, nullptr, nullptr, nullptr, d0, d1, d2, d3,
                   l, s, d, false);
      atomicAdd(&hist[l * nbk + (d >> NSH)], 1);
    }
  }
  __syncthreads();
  for (int i = tid; i < NB; i += 256) mat[(size_t)c * NB + i] = hist[i];
}

// Level 1b: per-bucket column scan of mat -> pfx (mat counts preserved),
// emits column totals.
__global__ __launch_bounds__(256) void colscan_a_kernel(
    const int* __restrict__ mat, int* __restrict__ pfx,
    int nchunk, int NB, int* __restrict__ colsum)
{
  __shared__ int col[512];
  __shared__ int aux[256];
  int gb = blockIdx.x, tid = threadIdx.x;
  for (int i = tid; i < nchunk; i += 256) col[i] = mat[(size_t)i * NB + gb];
  __syncthreads();
  int tot = lds_excl_scan(col, nchunk, aux, tid);
  for (int i = tid; i < nchunk; i += 256) pfx[(size_t)i * NB + gb] = col[i];
  if (tid == 0) colsum[gb] = tot;
}

__global__ __launch_bounds__(256) void colscan_b_kernel(
    const int* __restrict__ colsum, int NB, int* __restrict__ colscan)
{
  __shared__ int buf[512];
  __shared__ int aux[256];
  int tid = threadIdx.x;
  for (int i = tid; i < NB; i += 256) buf[i] = colsum[i];
  __syncthreads();
  int tot = lds_excl_scan(buf, NB, aux, tid);
  for (int i = tid; i < NB; i += 256) colscan[i] = buf[i];
  if (tid == 0) colscan[NB] = tot;
}

// Level 1c: scatter chunk items into bucket-major staging via LDS reorder.
__global__ __launch_bounds__(256) void scatter_kernel(
    const int* __restrict__ s0, const int* __restrict__ s1,
    const int* __restrict__ s2, const int* __restrict__ s3,
    const int* __restrict__ d0, const int* __restrict__ d1,
    const int* __restrict__ d2, const int* __restrict__ d3,
    int e0, int e1, int e2, int e3, int n, int nbk, int NB, int nitems,
    const int* __restrict__ mat, const int* __restrict__ pfx,
    const int* __restrict__ colscan, int* __restrict__ staging)
{
  __shared__ int lbuf[CHUNK];
  __shared__ int hist[512];    // within-chunk exclusive offsets
  __shared__ int cur[512];
  __shared__ int basex[512];
  __shared__ int aux[256];
  int tid = threadIdx.x, c = blockIdx.x;
  for (int i = tid; i < NB; i += 256) hist[i] = mat[(size_t)c * NB + i];
  __syncthreads();
  lds_excl_scan(hist, NB, aux, tid);
  for (int i = tid; i < NB; i += 256) {
    cur[i]   = hist[i];
    basex[i] = colscan[i] + pfx[(size_t)c * NB + i];
  }
  __syncthreads();
  int t1 = e0, t2 = t1 + e1, t3 = t2 + e2, t4 = t3 + e3;
  int base = c * CHUNK;
#pragma unroll
  for (int k = 0; k < CHUNK / 256; ++k) {
    int id = base + k * 256 + tid;
    if (id < nitems) {
      int l, s, d;
      resolve_item(id, t1, t2, t3, t4, n,
                   s0, s1, s2, s3, d0, d1, d2, d3, l, s, d, true);
      int gb = l * nbk + (d >> NSH);
      int p = atomicAdd(&cur[gb], 1);
      lbuf[p] = s | ((d & ((1 << NSH) - 1)) << 17);
    }
  }
  __syncthreads();
  // write out bucket runs (contiguous per bucket; coalesced within run)
  int wave = tid >> 6, lane = tid & 63;
  for (int gb = wave; gb < NB; gb += 4) {
    int st = hist[gb], en = cur[gb];
    int gbase = basex[gb];
    for (int j = lane; j < en - st; j += 64)
      staging[gbase + j] = lbuf[st + j];
  }
}

// Level 2: one block per (layer,bucket): node-level counting sort of the
// bucket's contiguous slice -> offs + final csr (block-local write window).
__global__ __launch_bounds__(256) void finalize_kernel(
    const int* __restrict__ staging, const int* __restrict__ colscan,
    int* __restrict__ offs4, int* __restrict__ csr4, int n, int nbk,
    int cb0, int cb1, int cb2, int cb3)
{
  __shared__ int cnt[1 << NSH];
  __shared__ int pos[1 << NSH];
  __shared__ int aux[256];
  int gb = blockIdx.x, tid = threadIdx.x;
  int l = gb / nbk, b = gb % nbk;
  int beg = colscan[gb], end = colscan[gb + 1];
  int node0 = b << NSH;
  int ncount = n - node0; if (ncount > (1 << NSH)) ncount = 1 << NSH;
  int cbl = (l == 0) ? cb0 : (l == 1) ? cb1 : (l == 2) ? cb2 : cb3;

  for (int i = tid; i < (1 << NSH); i += 256) cnt[i] = 0;
  __syncthreads();
  for (int t = beg + tid; t < end; t += 256)
    atomicAdd(&cnt[staging[t] >> 17], 1);
  __syncthreads();
  lds_excl_scan(cnt, 1 << NSH, aux, tid);
  for (int i = tid; i < (1 << NSH); i += 256) {
    if (i < ncount)
      offs4[(size_t)l * (n + 1) + node0 + i] = beg + cnt[i] - cbl;
    pos[i] = cnt[i];
  }
  __syncthreads();
  for (int t = beg + tid; t < end; t += 256) {
    int e = staging[t];
    int p = atomicAdd(&pos[e >> 17], 1);
    csr4[beg + p] = e & 0x1FFFF;
  }
}

// ---------------- fused GATv2 edge phase (R11 version) ---------------------
// SUBGROUP-PER-NODE: 16 lanes own one dst node (4 nodes/wave); each lane
// handles 8 dims. One edge per subgroup per iteration, 1-deep prefetch.
// exp2 domain (att pre-scaled by log2e). deg>=1 (self-loop) so the prologue
// gather is unconditional.
__global__ __launch_bounds__(256) void gat_dst_kernel(
    const unsigned short* __restrict__ xlb,
    const unsigned short* __restrict__ xrb,
    const int* __restrict__ offs, const int* __restrict__ csr,
    const float* __restrict__ att, const float* __restrict__ bias,
    float* __restrict__ hout_f, unsigned short* __restrict__ hout_b, int n)
{
  const float LOG2E = 1.4426950408889634f;
  int wid = (blockIdx.x * 256 + threadIdx.x) >> 4;   // subgroup id = node
  int c   = threadIdx.x & 15;                        // dim chunk c*8..c*8+7
  if (wid >= n) return;

  uint4 xru = *(const uint4*)(xrb + (size_t)wid * 128 + c * 8);
  float2 xr0 = unpk(xru.x), xr1 = unpk(xru.y);
  float2 xr2 = unpk(xru.z), xr3 = unpk(xru.w);
  const float2* att2 = (const float2*)att + c * 4;
  float2 a0 = att2[0], a1 = att2[1], a2 = att2[2], a3 = att2[3];
  a0.x *= LOG2E; a0.y *= LOG2E; a1.x *= LOG2E; a1.y *= LOG2E;
  a2.x *= LOG2E; a2.y *= LOG2E; a3.x *= LOG2E; a3.y *= LOG2E;

  int beg = offs[wid], end = offs[wid + 1];
  float ssum = 0.f;
  float2 ac0 = {0.f, 0.f}, ac1 = {0.f, 0.f};
  float2 ac2 = {0.f, 0.f}, ac3 = {0.f, 0.f};

  // prologue prefetch (deg >= 1 always)
  int s0 = csr[beg];
  uint4 xu = *(const uint4*)(xlb + (size_t)s0 * 128 + c * 8);

  for (int j = beg; j < end; ++j) {
    uint4 cu = xu;
    int jn = j + 1;
    if (jn < end) {                          // prefetch next (overlaps chain)
      int sn = csr[jn];
      xu = *(const uint4*)(xlb + (size_t)sn * 128 + c * 8);
    }
    float2 xs0 = unpk(cu.x), xs1 = unpk(cu.y);
    float2 xs2 = unpk(cu.z), xs3 = unpk(cu.w);
    float2 t0 = {xs0.x + xr0.x, xs0.y + xr0.y};
    float2 t1 = {xs1.x + xr1.x, xs1.y + xr1.y};
    float2 t2 = {xs2.x + xr2.x, xs2.y + xr2.y};
    float2 t3 = {xs3.x + xr3.x, xs3.y + xr3.y};
    t0.x = fmaxf(t0.x, 0.2f * t0.x); t0.y = fmaxf(t0.y, 0.2f * t0.y);
    t1.x = fmaxf(t1.x, 0.2f * t1.x); t1.y = fmaxf(t1.y, 0.2f * t1.y);
    t2.x = fmaxf(t2.x, 0.2f * t2.x); t2.y = fmaxf(t2.y, 0.2f * t2.y);
    t3.x = fmaxf(t3.x, 0.2f * t3.x); t3.y = fmaxf(t3.y, 0.2f * t3.y);
    float2 pp = {t0.x * a0.x, t0.y * a0.y};
    pp.x = fmaf(t1.x, a1.x, pp.x); pp.y = fmaf(t1.y, a1.y, pp.y);
    pp.x = fmaf(t2.x, a2.x, pp.x); pp.y = fmaf(t2.y, a2.y, pp.y);
    pp.x = fmaf(t3.x, a3.x, pp.x); pp.y = fmaf(t3.y, a3.y, pp.y);
    float part = pp.x + pp.y;
    part += __shfl_xor(part, 1, 64);         // 16-lane group reduction
    part += __shfl_xor(part, 2, 64);
    part += __shfl_xor(part, 4, 64);
    part += __shfl_xor(part, 8, 64);
    float p = __builtin_amdgcn_exp2f(part);  // att pre-scaled by log2e
    ssum += p;
    ac0.x = fmaf(p, xs0.x, ac0.x); ac0.y = fmaf(p, xs0.y, ac0.y);
    ac1.x = fmaf(p, xs1.x, ac1.x); ac1.y = fmaf(p, xs1.y, ac1.y);
    ac2.x = fmaf(p, xs2.x, ac2.x); ac2.y = fmaf(p, xs2.y, ac2.y);
    ac3.x = fmaf(p, xs3.x, ac3.x); ac3.y = fmaf(p, xs3.y, ac3.y);
  }

  float inv = 1.0f / ssum;
  float o[8] = {ac0.x, ac0.y, ac1.x, ac1.y, ac2.x, ac2.y, ac3.x, ac3.y};
#pragma unroll
  for (int k = 0; k < 8; ++k) o[k] = fmaf(o[k], inv, bias[c * 8 + k]);

  if (hout_f) {
    float4 v0 = make_float4(o[0], o[1], o[2], o[3]);
    float4 v1 = make_float4(o[4], o[5], o[6], o[7]);
    *(float4*)(hout_f + (size_t)wid * 128 + c * 8)     = v0;
    *(float4*)(hout_f + (size_t)wid * 128 + c * 8 + 4) = v1;
  } else {
    bf16x8 ob;
#pragma unroll
    for (int k = 0; k < 8; ++k) ob[k] = (short)f2bf(o[k]);
    *(bf16x8*)(hout_b + (size_t)wid * 128 + c * 8) = ob;
  }
}

// ---------------- two-stage pooling + fused reduce+output GEMM -------------
__global__ __launch_bounds__(256) void pool_partial_kernel(
    const float* __restrict__ h, const int* __restrict__ gnode,
    const int* __restrict__ bidx, float* __restrict__ partial, int ng)
{
  __shared__ float acc[64 * 128];           // 32 KiB
  int tid = threadIdx.x;
  for (int t = tid; t < 64 * 128; t += 256) acc[t] = 0.f;
  __syncthreads();
  int col = tid & 127, half = tid >> 7;
  for (int nd = blockIdx.x * 2 + half; nd < ng; nd += gridDim.x * 2) {
    int row = gnode[nd];
    int g   = bidx[nd];
    atomicAdd(&acc[g * 128 + col], h[(size_t)row * 128 + col]);
  }
  __syncthreads();
  float* out = partial + (size_t)blockIdx.x * 8192;
  for (int t = tid; t < 64 * 128; t += 256) out[t] = acc[t];
}

// one block per graph g: reduce partials for row g, then out[g] = pooled@W+b
__global__ __launch_bounds__(128) void pool_out_kernel(
    const float* __restrict__ partial, const float* __restrict__ W,
    const float* __restrict__ b, float* __restrict__ out)
{
  __shared__ float pr[128];
  int g = blockIdx.x, tid = threadIdx.x;    // tid = col
  float s = 0.f;
  for (int p = 0; p < POOLP; ++p) s += partial[(size_t)p * 8192 + g * 128 + tid];
  pr[tid] = s;
  __syncthreads();
  if (tid < 16) {
    float acc = b[tid];
#pragma unroll
    for (int k = 0; k < 128; ++k) acc += pr[k] * W[k * 16 + tid];
    out[g * 16 + tid] = acc;
  }
}

// ---------------------------------------------------------------------------
extern "C" void kernel_launch(void* const* d_in, const int* in_sizes, int n_in,
                              void* d_out, int out_size, void* d_ws, size_t ws_size,
                              hipStream_t stream)
{
  const float* x    = (const float*)d_in[0];
  const int* ei0    = (const int*)d_in[1];   // edge_index            [2,1e6]
  const int* ei_sg  = (const int*)d_in[2];   // subgraph_edge_index   [2,1e6]
  const int* ei_ns  = (const int*)d_in[3];   // node_subnode_index    [2,2e5]
  const int* ei_sn  = (const int*)d_in[4];   // subnode_node_index    [2,2e5]
  const int* gnode  = (const int*)d_in[5];   // ground_node
  // d_in[6] = subgraph_batch_index (unused by reference)
  const int* bidx   = (const int*)d_in[7];   // batch_idx
  const float* embW = (const float*)d_in[8];
  const float* embB = (const float*)d_in[9];
  const float* Wl   = (const float*)d_in[10];
  const float* Wr   = (const float*)d_in[11];
  const float* att  = (const float*)d_in[12];
  const float* bias = (const float*)d_in[13];
  const float* outW = (const float*)d_in[14];
  const float* outB = (const float*)d_in[15];

  const int n  = in_sizes[0] / 32;           // 100000
  const int ng = in_sizes[5];                // 40000

  // reference layer order: edge_index, node_subnode, subgraph_edge, subnode_node
  const int  E_arr[4] = { in_sizes[1] / 2, in_sizes[3] / 2,
                          in_sizes[2] / 2, in_sizes[4] / 2 };
  const int* eptr[4]  = { ei0, ei_ns, ei_sg, ei_sn };
  const int E_tot  = E_arr[0] + E_arr[1] + E_arr[2] + E_arr[3];
  const int nitems = E_tot + 4 * n;
  const int nbk    = (n + (1 << NSH) - 1) >> NSH;   // buckets per layer (98)
  const int NB     = 4 * nbk;                       // global buckets (392)
  const int nchunk = (nitems + CHUNK - 1) / CHUNK;  // 342
  // per-layer bases into csr/staging (layer l slice: E_l + n items)
  int cb[4];
  cb[0] = 0;
  for (int i = 1; i < 4; ++i) cb[i] = cb[i - 1] + E_arr[i - 1] + n;

  // workspace carve (bump allocator, 256B aligned)
  char* ws = (char*)d_ws;
  size_t off = 0;
  auto alloc = [&](size_t bytes) -> void* {
    void* p = ws + off;
    off = (off + bytes + 255) & ~(size_t)255;
    return p;
  };
  float*          h      = (float*)alloc((size_t)n * 128 * sizeof(float));
  unsigned short* hb     = (unsigned short*)alloc((size_t)n * 128 * sizeof(unsigned short));
  unsigned short* xlb    = (unsigned short*)alloc((size_t)n * 128 * sizeof(unsigned short));
  unsigned short* xrb    = (unsigned short*)alloc((size_t)n * 128 * sizeof(unsigned short));
  int*            offs4  = (int*)alloc((size_t)4 * (n + 1) * sizeof(int));
  int*            mat    = (int*)alloc((size_t)nchunk * NB * sizeof(int));
  int*            pfx    = (int*)alloc((size_t)nchunk * NB * sizeof(int));
  int*            colsum = (int*)alloc((size_t)NB * sizeof(int));
  int*            colscan= (int*)alloc((size_t)(NB + 1) * sizeof(int));
  int*            staging= (int*)alloc((size_t)nitems * sizeof(int));
  int*            csr4   = (int*)alloc((size_t)nitems * sizeof(int));
  unsigned short* packB  = (unsigned short*)alloc(131072 * sizeof(unsigned short));
  unsigned short* packE  = (unsigned short*)alloc(4096 * sizeof(unsigned short));
  float*          partial= (float*)alloc((size_t)POOLP * 8192 * sizeof(float));
  (void)ws_size; (void)n_in; (void)out_size;

  // dst rows of each edge list
  const int* D[4] = { eptr[0] + E_arr[0], eptr[1] + E_arr[1],
                      eptr[2] + E_arr[2], eptr[3] + E_arr[3] };

  int setup_items = 131072 + 4096 + 4;
  setup_kernel<<<(setup_items + 255) / 256, 256, 0, stream>>>(
      Wl, Wr, embW, packB, packE, offs4, n,
      E_arr[0], E_arr[1], E_arr[2], E_arr[3]);

  const int ntile16 = (n + 15) / 16;
  embed_mfma_kernel<<<(ntile16 + 3) / 4, 256, 0, stream>>>(
      x, packE, embB, hb, n);

  // atomic-free radix-partition CSR build (all 4 graphs)
  hist_kernel<<<nchunk, 256, 0, stream>>>(
      D[0], D[1], D[2], D[3], E_arr[0], E_arr[1], E_arr[2], E_arr[3],
      n, nbk, NB, nitems, mat);
  colscan_a_kernel<<<NB, 256, 0, stream>>>(mat, pfx, nchunk, NB, colsum);
  colscan_b_kernel<<<1, 256, 0, stream>>>(colsum, NB, colscan);
  scatter_kernel<<<nchunk, 256, 0, stream>>>(
      eptr[0], eptr[1], eptr[2], eptr[3], D[0], D[1], D[2], D[3],
      E_arr[0], E_arr[1], E_arr[2], E_arr[3], n, nbk, NB, nitems,
      mat, pfx, colscan, staging);
  finalize_kernel<<<NB, 256, 0, stream>>>(
      staging, colscan, offs4, csr4, n, nbk, cb[0], cb[1], cb[2], cb[3]);

  const int gemm_grid = (ntile16 + 1) / 2;          // 2 node-tiles per block
  for (int l = 0; l < 4; ++l) {
    gemm_mfma_kernel<<<gemm_grid, 256, 0, stream>>>(
        hb, packB + (size_t)l * 32768, xlb, xrb, n);
    gat_dst_kernel<<<((size_t)n * 16 + 255) / 256, 256, 0, stream>>>(
        xlb, xrb, offs4 + (size_t)l * (n + 1), csr4 + cb[l],
        att + (size_t)l * 128, bias + (size_t)l * 128,
        (l == 3) ? h : nullptr, (l < 3) ? hb : nullptr, n);
  }

  pool_partial_kernel<<<POOLP, 256, 0, stream>>>(h, gnode, bidx, partial, ng);
  pool_out_kernel<<<64, 128, 0, stream>>>(partial, outW, outB, (float*)d_out);
}

// Round 14
// 494.018 us; speedup vs baseline: 1.1220x; 1.0921x over previous
//
#include <hip/hip_runtime.h>
#include <cstddef>

// ---------------------------------------------------------------------------
// TransformerNet: 4-layer GATv2 GNN on MI355X (gfx950).
// R14: gemm reverted to R11 row-output (R13 proved transposed-gemm's strided
// 8B stores cost +27us) + LDS-staged hb tile: 32 rows staged coalesced once
// per block (shared by all 4 waves, 4x fewer global reads), A-frags via
// ds_read_b128 from padded rows (stride 136 shorts -> 2-way bank alias,
// free). Everything else identical to R11/R13.
// ---------------------------------------------------------------------------

typedef __attribute__((ext_vector_type(8))) short bf16x8;  // 8 bf16 = 4 VGPR
typedef __attribute__((ext_vector_type(4))) float f32x4;

#define NSH   10              // nodes-per-bucket shift (1024)
#define CHUNK 8192            // items per partition chunk
#define POOLP 256             // pool stage-1 blocks

__device__ __forceinline__ unsigned short f2bf(float f) {
  unsigned int u = __float_as_uint(f);
  u += 0x7fffu + ((u >> 16) & 1u);            // round-to-nearest-even
  return (unsigned short)(u >> 16);
}
__device__ __forceinline__ unsigned short f2bf_rtz(float f) {
  return (unsigned short)(__float_as_uint(f) >> 16);   // truncate (1 inst)
}
__device__ __forceinline__ float bf2f(short s) {
  return __uint_as_float(((unsigned int)(unsigned short)s) << 16);
}
// unpack packed pair of bf16 (one uint32) -> float2 (1 VALU inst per element)
__device__ __forceinline__ float2 unpk(unsigned int u) {
  return make_float2(__uint_as_float(u << 16),
                     __uint_as_float(u & 0xFFFF0000u));
}

// exclusive scan of a[0..len) in LDS with 256 threads; a rewritten in place;
// returns total. aux = 256-int scratch. len <= 1024.
__device__ __forceinline__ int lds_excl_scan(int* a, int len, int* aux, int tid)
{
  int g = (len + 255) >> 8;                   // elements per thread
  int lo = tid * g;
  int s = 0;
  for (int i = 0; i < g; ++i) { int idx = lo + i; if (idx < len) s += a[idx]; }
  aux[tid] = s;
  __syncthreads();
  for (int d = 1; d < 256; d <<= 1) {
    int v = (tid >= d) ? aux[tid - d] : 0;
    __syncthreads();
    aux[tid] += v;
    __syncthreads();
  }
  int run = aux[tid] - s;                     // exclusive base of this span
  for (int i = 0; i < g; ++i) {
    int idx = lo + i;
    if (idx < len) { int t = a[idx]; a[idx] = run; run += t; }
  }
  int total = aux[255];
  __syncthreads();
  return total;
}

// resolve item id -> (layer, src, dst). Items = all edges then 4*n self-loops.
__device__ __forceinline__ void resolve_item(
    int id, int t1, int t2, int t3, int t4, int n,
    const int* s0, const int* s1, const int* s2, const int* s3,
    const int* d0, const int* d1, const int* d2, const int* d3,
    int& l, int& s, int& d, bool need_src)
{
  if (id < t4) {
    const int *sp, *dp; int e;
    if      (id < t1) { l = 0; e = id;      sp = s0; dp = d0; }
    else if (id < t2) { l = 1; e = id - t1; sp = s1; dp = d1; }
    else if (id < t3) { l = 2; e = id - t2; sp = s2; dp = d2; }
    else              { l = 3; e = id - t3; sp = s3; dp = d3; }
    d = dp[e];
    s = need_src ? sp[e] : 0;
  } else {
    int k = id - t4;
    l = (k >= 3 * n) ? 3 : (k >= 2 * n) ? 2 : (k >= n) ? 1 : 0;
    s = k - l * n; d = s;                     // self-loop
  }
}

// ------- setup: pack layer W + embed W + offs4 layer-end sentinels ---------
// packB[ct=16][kt=4][lane=64][j=8] per layer; element = W[k][col],
// k = kt*32 + (lane>>4)*8 + j, col = ct*16 + (lane&15); ct<8 -> Wl, else Wr.
__global__ __launch_bounds__(256) void setup_kernel(
    const float* __restrict__ Wl, const float* __restrict__ Wr,
    const float* __restrict__ embW,
    unsigned short* __restrict__ packB, unsigned short* __restrict__ packE,
    int* __restrict__ offs4, int n, int e0, int e1, int e2, int e3)
{
  int id = blockIdx.x * 256 + threadIdx.x;
  if (id < 131072) {
    int j    = id & 7;
    int lane = (id >> 3) & 63;
    int kt   = (id >> 9) & 3;
    int ct   = (id >> 11) & 15;
    int l    = id >> 15;
    int k    = kt * 32 + (lane >> 4) * 8 + j;
    int col  = ct * 16 + (lane & 15);
    float v = (ct < 8) ? Wl[(size_t)l * 16384 + k * 128 + col]
                       : Wr[(size_t)l * 16384 + k * 128 + (col - 128)];
    packB[id] = f2bf(v);
  }
  int pe = id - 131072;
  if (pe >= 0 && pe < 4096) {
    int j    = pe & 7;
    int lane = (pe >> 3) & 63;
    int ct   = pe >> 9;
    int k    = (lane >> 4) * 8 + j;
    int col  = ct * 16 + (lane & 15);
    packE[pe] = f2bf(embW[k * 128 + col]);
  }
  int q = pe - 4096;
  if (q >= 0 && q < 4) {
    int El = (q == 0) ? e0 : (q == 1) ? e1 : (q == 2) ? e2 : e3;
    offs4[(size_t)q * (n + 1) + n] = El + n;
  }
}

// ------- embed GEMM (MFMA): hb[n,128](bf16) = x[n,32] @ embW + b -----------
__global__ __launch_bounds__(256) void embed_mfma_kernel(
    const float* __restrict__ x, const unsigned short* __restrict__ packE,
    const float* __restrict__ b, unsigned short* __restrict__ hb, int n)
{
  const int wave = threadIdx.x >> 6;
  const int lane = threadIdx.x & 63;
  const int rlan = lane & 15;
  const int kgrp = lane >> 4;

  bf16x8 Bf[8];
#pragma unroll
  for (int ct = 0; ct < 8; ++ct)
    Bf[ct] = *(const bf16x8*)(packE + ((size_t)ct * 64 + lane) * 8);
  float bv[8];
#pragma unroll
  for (int ct = 0; ct < 8; ++ct) bv[ct] = b[ct * 16 + rlan];

  const float4* __restrict__ x4 = (const float4*)x;
  const int ntiles = (n + 15) / 16;
  for (int tile = blockIdx.x * 4 + wave; tile < ntiles; tile += gridDim.x * 4) {
    int r = tile * 16 + rlan;
    if (r >= n) r = n - 1;                    // clamp (writes are guarded)
    float4 a0 = x4[(size_t)r * 8 + kgrp * 2];
    float4 a1 = x4[(size_t)r * 8 + kgrp * 2 + 1];
    bf16x8 Af;
    Af[0] = (short)f2bf(a0.x); Af[1] = (short)f2bf(a0.y);
    Af[2] = (short)f2bf(a0.z); Af[3] = (short)f2bf(a0.w);
    Af[4] = (short)f2bf(a1.x); Af[5] = (short)f2bf(a1.y);
    Af[6] = (short)f2bf(a1.z); Af[7] = (short)f2bf(a1.w);

    f32x4 acc[8];
#pragma unroll
    for (int ct = 0; ct < 8; ++ct) {
      acc[ct] = (f32x4){0.f, 0.f, 0.f, 0.f};
      acc[ct] = __builtin_amdgcn_mfma_f32_16x16x32_bf16(Af, Bf[ct], acc[ct], 0, 0, 0);
    }
    // C/D: col = lane&15, row = kgrp*4 + reg
    int rowb = tile * 16 + kgrp * 4;
#pragma unroll
    for (int ct = 0; ct < 8; ++ct) {
      int col = ct * 16 + rlan;
#pragma unroll
      for (int rr = 0; rr < 4; ++rr)
        if (rowb + rr < n)
          hb[(size_t)(rowb + rr) * 128 + col] = f2bf(acc[ct][rr] + bv[ct]);
    }
  }
}

// ------ layer GEMM (MFMA, row-output + LDS-staged A): [xl|xr] = hb @ W -----
// Block stages 32 hb rows coalesced into LDS (padded stride 136 shorts);
// all 4 waves read A-frags from LDS (ds_read_b128, 2-way alias = free).
// Wave w owns 64 cols: w<2 -> xlb, w>=2 -> xrb. Stores = R11 row-output
// (32B-contiguous per 16-lane group).
#define GPAD 136              // padded row stride in shorts (272B)
__global__ __launch_bounds__(256) void gemm_mfma_kernel(
    const unsigned short* __restrict__ hb,
    const unsigned short* __restrict__ packB,   // this layer's [16][4][64][8]
    unsigned short* __restrict__ xlb, unsigned short* __restrict__ xrb, int n)
{
  __shared__ unsigned short hs[32 * GPAD];    // 8.5 KB
  const int tid  = threadIdx.x;
  const int wave = tid >> 6;
  const int lane = tid & 63;
  const int rlan = lane & 15;
  const int kgrp = lane >> 4;

  bf16x8 Bf[4][4];
#pragma unroll
  for (int ct = 0; ct < 4; ++ct)
#pragma unroll
    for (int kt = 0; kt < 4; ++kt)
      Bf[ct][kt] = *(const bf16x8*)(packB +
          ((((size_t)(wave * 4 + ct)) * 4 + kt) * 64 + lane) * 8);

  unsigned short* __restrict__ outp = (wave < 2) ? xlb : xrb;  // wave-uniform
  const int colbase = (wave & 1) * 64;

  const int ntiles = (n + 31) / 32;
  for (int tile = blockIdx.x; tile < ntiles; tile += gridDim.x) {
    const int row0 = tile * 32;
    __syncthreads();                          // hs safe to overwrite
    // stage 32 rows (8192 shorts) coalesced: 4 x uint4 per thread
#pragma unroll
    for (int i = 0; i < 4; ++i) {
      int g  = (i * 256 + tid) * 8;           // short index within tile
      int r  = g >> 7;                        // row 0..31
      int cc = g & 127;                       // col 0..120
      int gr = row0 + r; if (gr >= n) gr = n - 1;
      uint4 v = *(const uint4*)(hb + (size_t)gr * 128 + cc);
      *(uint4*)(hs + r * GPAD + cc) = v;
    }
    __syncthreads();

    bf16x8 Af[2][4];
#pragma unroll
    for (int rt = 0; rt < 2; ++rt)
#pragma unroll
      for (int kt = 0; kt < 4; ++kt)
        Af[rt][kt] = *(const bf16x8*)(hs + (rt * 16 + rlan) * GPAD
                                         + kgrp * 8 + kt * 32);

    f32x4 acc[2][4];
#pragma unroll
    for (int rt = 0; rt < 2; ++rt)
#pragma unroll
      for (int ct = 0; ct < 4; ++ct)
        acc[rt][ct] = (f32x4){0.f, 0.f, 0.f, 0.f};
#pragma unroll
    for (int kt = 0; kt < 4; ++kt)
#pragma unroll
      for (int rt = 0; rt < 2; ++rt)
#pragma unroll
        for (int ct = 0; ct < 4; ++ct)
          acc[rt][ct] = __builtin_amdgcn_mfma_f32_16x16x32_bf16(
              Af[rt][kt], Bf[ct][kt], acc[rt][ct], 0, 0, 0);
    // C/D: col = lane&15, row = kgrp*4 + reg
#pragma unroll
    for (int rt = 0; rt < 2; ++rt) {
      int rowb = row0 + rt * 16 + kgrp * 4;
#pragma unroll
      for (int ct = 0; ct < 4; ++ct) {
        int col = colbase + ct * 16 + rlan;
        size_t base = (size_t)rowb * 128 + col;
#pragma unroll
        for (int r = 0; r < 4; ++r)
          if (rowb + r < n)
            outp[base + (size_t)r * 128] = f2bf_rtz(acc[rt][ct][r]);
      }
    }
  }
}

// ---------------- radix-partition CSR build --------------------------------
// Level 1a: per-chunk histogram over NB = 4*nbk global buckets.
__global__ __launch_bounds__(256) void hist_kernel(
    const int* __restrict__ d0, const int* __restrict__ d1,
    const int* __restrict__ d2, const int* __restrict__ d3,
    int e0, int e1, int e2, int e3, int n, int nbk, int NB, int nitems,
    int* __restrict__ mat)
{
  __shared__ int hist[512];
  int tid = threadIdx.x, c = blockIdx.x;
  for (int i = tid; i < NB; i += 256) hist[i] = 0;
  __syncthreads();
  int t1 = e0, t2 = t1 + e1, t3 = t2 + e2, t4 = t3 + e3;
  int base = c * CHUNK;
#pragma unroll
  for (int k = 0; k < CHUNK / 256; ++k) {
    int id = base + k * 256 + tid;
    if (id < nitems) {
      int l, s, d;
      resolve_item(id, t1, t2, t3, t4, n,
                   nullptr, nullptr, nullptr, nullptr, d0, d1, d2, d3,
                   l, s, d, false);
      atomicAdd(&hist[l * nbk + (d >> NSH)], 1);
    }
  }
  __syncthreads();
  for (int i = tid; i < NB; i += 256) mat[(size_t)c * NB + i] = hist[i];
}

// Level 1b: per-bucket column scan of mat -> pfx (mat counts preserved),
// emits column totals.
__global__ __launch_bounds__(256) void colscan_a_kernel(
    const int* __restrict__ mat, int* __restrict__ pfx,
    int nchunk, int NB, int* __restrict__ colsum)
{
  __shared__ int col[512];
  __shared__ int aux[256];
  int gb = blockIdx.x, tid = threadIdx.x;
  for (int i = tid; i < nchunk; i += 256) col[i] = mat[(size_t)i * NB + gb];
  __syncthreads();
  int tot = lds_excl_scan(col, nchunk, aux, tid);
  for (int i = tid; i < nchunk; i += 256) pfx[(size_t)i * NB + gb] = col[i];
  if (tid == 0) colsum[gb] = tot;
}

__global__ __launch_bounds__(256) void colscan_b_kernel(
    const int* __restrict__ colsum, int NB, int* __restrict__ colscan)
{
  __shared__ int buf[512];
  __shared__ int aux[256];
  int tid = threadIdx.x;
  for (int i = tid; i < NB; i += 256) buf[i] = colsum[i];
  __syncthreads();
  int tot = lds_excl_scan(buf, NB, aux, tid);
  for (int i = tid; i < NB; i += 256) colscan[i] = buf[i];
  if (tid == 0) colscan[NB] = tot;
}

// Level 1c: scatter chunk items into bucket-major staging via LDS reorder.
__global__ __launch_bounds__(256) void scatter_kernel(
    const int* __restrict__ s0, const int* __restrict__ s1,
    const int* __restrict__ s2, const int* __restrict__ s3,
    const int* __restrict__ d0, const int* __restrict__ d1,
    const int* __restrict__ d2, const int* __restrict__ d3,
    int e0, int e1, int e2, int e3, int n, int nbk, int NB, int nitems,
    const int* __restrict__ mat, const int* __restrict__ pfx,
    const int* __restrict__ colscan, int* __restrict__ staging)
{
  __shared__ int lbuf[CHUNK];
  __shared__ int hist[512];    // within-chunk exclusive offsets
  __shared__ int cur[512];
  __shared__ int basex[512];
  __shared__ int aux[256];
  int tid = threadIdx.x, c = blockIdx.x;
  for (int i = tid; i < NB; i += 256) hist[i] = mat[(size_t)c * NB + i];
  __syncthreads();
  lds_excl_scan(hist, NB, aux, tid);
  for (int i = tid; i < NB; i += 256) {
    cur[i]   = hist[i];
    basex[i] = colscan[i] + pfx[(size_t)c * NB + i];
  }
  __syncthreads();
  int t1 = e0, t2 = t1 + e1, t3 = t2 + e2, t4 = t3 + e3;
  int base = c * CHUNK;
#pragma unroll
  for (int k = 0; k < CHUNK / 256; ++k) {
    int id = base + k * 256 + tid;
    if (id < nitems) {
      int l, s, d;
      resolve_item(id, t1, t2, t3, t4, n,
                   s0, s1, s2, s3, d0, d1, d2, d3, l, s, d, true);
      int gb = l * nbk + (d >> NSH);
      int p = atomicAdd(&cur[gb], 1);
      lbuf[p] = s | ((d & ((1 << NSH) - 1)) << 17);
    }
  }
  __syncthreads();
  // write out bucket runs (contiguous per bucket; coalesced within run)
  int wave = tid >> 6, lane = tid & 63;
  for (int gb = wave; gb < NB; gb += 4) {
    int st = hist[gb], en = cur[gb];
    int gbase = basex[gb];
    for (int j = lane; j < en - st; j += 64)
      staging[gbase + j] = lbuf[st + j];
  }
}

// Level 2: one block per (layer,bucket): node-level counting sort of the
// bucket's contiguous slice -> offs + final csr (block-local write window).
__global__ __launch_bounds__(256) void finalize_kernel(
    const int* __restrict__ staging, const int* __restrict__ colscan,
    int* __restrict__ offs4, int* __restrict__ csr4, int n, int nbk,
    int cb0, int cb1, int cb2, int cb3)
{
  __shared__ int cnt[1 << NSH];
  __shared__ int pos[1 << NSH];
  __shared__ int aux[256];
  int gb = blockIdx.x, tid = threadIdx.x;
  int l = gb / nbk, b = gb % nbk;
  int beg = colscan[gb], end = colscan[gb + 1];
  int node0 = b << NSH;
  int ncount = n - node0; if (ncount > (1 << NSH)) ncount = 1 << NSH;
  int cbl = (l == 0) ? cb0 : (l == 1) ? cb1 : (l == 2) ? cb2 : cb3;

  for (int i = tid; i < (1 << NSH); i += 256) cnt[i] = 0;
  __syncthreads();
  for (int t = beg + tid; t < end; t += 256)
    atomicAdd(&cnt[staging[t] >> 17], 1);
  __syncthreads();
  lds_excl_scan(cnt, 1 << NSH, aux, tid);
  for (int i = tid; i < (1 << NSH); i += 256) {
    if (i < ncount)
      offs4[(size_t)l * (n + 1) + node0 + i] = beg + cnt[i] - cbl;
    pos[i] = cnt[i];
  }
  __syncthreads();
  for (int t = beg + tid; t < end; t += 256) {
    int e = staging[t];
    int p = atomicAdd(&pos[e >> 17], 1);
    csr4[beg + p] = e & 0x1FFFF;
  }
}

// ---------------- fused GATv2 edge phase (R11 version) ---------------------
// SUBGROUP-PER-NODE: 16 lanes own one dst node (4 nodes/wave); each lane
// handles 8 dims. One edge per subgroup per iteration, 1-deep prefetch.
// exp2 domain (att pre-scaled by log2e).
__global__ __launch_bounds__(256) void gat_dst_kernel(
    const unsigned short* __restrict__ xlb,
    const unsigned short* __restrict__ xrb,
    const int* __restrict__ offs, const int* __restrict__ csr,
    const float* __restrict__ att, const float* __restrict__ bias,
    float* __restrict__ hout_f, unsigned short* __restrict__ hout_b, int n)
{
  const float LOG2E = 1.4426950408889634f;
  int wid = (blockIdx.x * 256 + threadIdx.x) >> 4;   // subgroup id = node
  int c   = threadIdx.x & 15;                        // dim chunk c*8..c*8+7
  if (wid >= n) return;

  uint4 xru = *(const uint4*)(xrb + (size_t)wid * 128 + c * 8);
  float2 xr0 = unpk(xru.x), xr1 = unpk(xru.y);
  float2 xr2 = unpk(xru.z), xr3 = unpk(xru.w);
  const float2* att2 = (const float2*)att + c * 4;
  float2 a0 = att2[0], a1 = att2[1], a2 = att2[2], a3 = att2[3];
  a0.x *= LOG2E; a0.y *= LOG2E; a1.x *= LOG2E; a1.y *= LOG2E;
  a2.x *= LOG2E; a2.y *= LOG2E; a3.x *= LOG2E; a3.y *= LOG2E;

  int beg = offs[wid], end = offs[wid + 1];
  float ssum = 0.f;
  float2 ac0 = {0.f, 0.f}, ac1 = {0.f, 0.f};
  float2 ac2 = {0.f, 0.f}, ac3 = {0.f, 0.f};

  // prologue prefetch (deg >= 1 always)
  int s0 = csr[beg];
  uint4 xu = *(const uint4*)(xlb + (size_t)s0 * 128 + c * 8);

  for (int j = beg; j < end; ++j) {
    uint4 cu = xu;
    int jn = j + 1;
    if (jn < end) {                          // prefetch next (overlaps chain)
      int sn = csr[jn];
      xu = *(const uint4*)(xlb + (size_t)sn * 128 + c * 8);
    }
    float2 xs0 = unpk(cu.x), xs1 = unpk(cu.y);
    float2 xs2 = unpk(cu.z), xs3 = unpk(cu.w);
    float2 t0 = {xs0.x + xr0.x, xs0.y + xr0.y};
    float2 t1 = {xs1.x + xr1.x, xs1.y + xr1.y};
    float2 t2 = {xs2.x + xr2.x, xs2.y + xr2.y};
    float2 t3 = {xs3.x + xr3.x, xs3.y + xr3.y};
    t0.x = fmaxf(t0.x, 0.2f * t0.x); t0.y = fmaxf(t0.y, 0.2f * t0.y);
    t1.x = fmaxf(t1.x, 0.2f * t1.x); t1.y = fmaxf(t1.y, 0.2f * t1.y);
    t2.x = fmaxf(t2.x, 0.2f * t2.x); t2.y = fmaxf(t2.y, 0.2f * t2.y);
    t3.x = fmaxf(t3.x, 0.2f * t3.x); t3.y = fmaxf(t3.y, 0.2f * t3.y);
    float2 pp = {t0.x * a0.x, t0.y * a0.y};
    pp.x = fmaf(t1.x, a1.x, pp.x); pp.y = fmaf(t1.y, a1.y, pp.y);
    pp.x = fmaf(t2.x, a2.x, pp.x); pp.y = fmaf(t2.y, a2.y, pp.y);
    pp.x = fmaf(t3.x, a3.x, pp.x); pp.y = fmaf(t3.y, a3.y, pp.y);
    float part = pp.x + pp.y;
    part += __shfl_xor(part, 1, 64);         // 16-lane group reduction
    part += __shfl_xor(part, 2, 64);
    part += __shfl_xor(part, 4, 64);
    part += __shfl_xor(part, 8, 64);
    float p = __builtin_amdgcn_exp2f(part);  // att pre-scaled by log2e
    ssum += p;
    ac0.x = fmaf(p, xs0.x, ac0.x); ac0.y = fmaf(p, xs0.y, ac0.y);
    ac1.x = fmaf(p, xs1.x, ac1.x); ac1.y = fmaf(p, xs1.y, ac1.y);
    ac2.x = fmaf(p, xs2.x, ac2.x); ac2.y = fmaf(p, xs2.y, ac2.y);
    ac3.x = fmaf(p, xs3.x, ac3.x); ac3.y = fmaf(p, xs3.y, ac3.y);
  }

  float inv = 1.0f / ssum;
  float o[8] = {ac0.x, ac0.y, ac1.x, ac1.y, ac2.x, ac2.y, ac3.x, ac3.y};
#pragma unroll
  for (int k = 0; k < 8; ++k) o[k] = fmaf(o[k], inv, bias[c * 8 + k]);

  if (hout_f) {
    float4 v0 = make_float4(o[0], o[1], o[2], o[3]);
    float4 v1 = make_float4(o[4], o[5], o[6], o[7]);
    *(float4*)(hout_f + (size_t)wid * 128 + c * 8)     = v0;
    *(float4*)(hout_f + (size_t)wid * 128 + c * 8 + 4) = v1;
  } else {
    bf16x8 ob;
#pragma unroll
    for (int k = 0; k < 8; ++k) ob[k] = (short)f2bf(o[k]);
    *(bf16x8*)(hout_b + (size_t)wid * 128 + c * 8) = ob;
  }
}

// ---------------- two-stage pooling + fused reduce+output GEMM -------------
__global__ __launch_bounds__(256) void pool_partial_kernel(
    const float* __restrict__ h, const int* __restrict__ gnode,
    const int* __restrict__ bidx, float* __restrict__ partial, int ng)
{
  __shared__ float acc[64 * 128];           // 32 KiB
  int tid = threadIdx.x;
  for (int t = tid; t < 64 * 128; t += 256) acc[t] = 0.f;
  __syncthreads();
  int col = tid & 127, half = tid >> 7;
  for (int nd = blockIdx.x * 2 + half; nd < ng; nd += gridDim.x * 2) {
    int row = gnode[nd];
    int g   = bidx[nd];
    atomicAdd(&acc[g * 128 + col], h[(size_t)row * 128 + col]);
  }
  __syncthreads();
  float* out = partial + (size_t)blockIdx.x * 8192;
  for (int t = tid; t < 64 * 128; t += 256) out[t] = acc[t];
}

// one block per graph g: reduce partials for row g, then out[g] = pooled@W+b
__global__ __launch_bounds__(128) void pool_out_kernel(
    const float* __restrict__ partial, const float* __restrict__ W,
    const float* __restrict__ b, float* __restrict__ out)
{
  __shared__ float pr[128];
  int g = blockIdx.x, tid = threadIdx.x;    // tid = col
  float s = 0.f;
  for (int p = 0; p < POOLP; ++p) s += partial[(size_t)p * 8192 + g * 128 + tid];
  pr[tid] = s;
  __syncthreads();
  if (tid < 16) {
    float acc = b[tid];
#pragma unroll
    for (int k = 0; k < 128; ++k) acc += pr[k] * W[k * 16 + tid];
    out[g * 16 + tid] = acc;
  }
}

// ---------------------------------------------------------------------------
extern "C" void kernel_launch(void* const* d_in, const int* in_sizes, int n_in,
                              void* d_out, int out_size, void* d_ws, size_t ws_size,
                              hipStream_t stream)
{
  const float* x    = (const float*)d_in[0];
  const int* ei0    = (const int*)d_in[1];   // edge_index            [2,1e6]
  const int* ei_sg  = (const int*)d_in[2];   // subgraph_edge_index   [2,1e6]
  const int* ei_ns  = (const int*)d_in[3];   // node_subnode_index    [2,2e5]
  const int* ei_sn  = (const int*)d_in[4];   // subnode_node_index    [2,2e5]
  const int* gnode  = (const int*)d_in[5];   // ground_node
  // d_in[6] = subgraph_batch_index (unused by reference)
  const int* bidx   = (const int*)d_in[7];   // batch_idx
  const float* embW = (const float*)d_in[8];
  const float* embB = (const float*)d_in[9];
  const float* Wl   = (const float*)d_in[10];
  const float* Wr   = (const float*)d_in[11];
  const float* att  = (const float*)d_in[12];
  const float* bias = (const float*)d_in[13];
  const float* outW = (const float*)d_in[14];
  const float* outB = (const float*)d_in[15];

  const int n  = in_sizes[0] / 32;           // 100000
  const int ng = in_sizes[5];                // 40000

  // reference layer order: edge_index, node_subnode, subgraph_edge, subnode_node
  const int  E_arr[4] = { in_sizes[1] / 2, in_sizes[3] / 2,
                          in_sizes[2] / 2, in_sizes[4] / 2 };
  const int* eptr[4]  = { ei0, ei_ns, ei_sg, ei_sn };
  const int E_tot  = E_arr[0] + E_arr[1] + E_arr[2] + E_arr[3];
  const int nitems = E_tot + 4 * n;
  const int nbk    = (n + (1 << NSH) - 1) >> NSH;   // buckets per layer (98)
  const int NB     = 4 * nbk;                       // global buckets (392)
  const int nchunk = (nitems + CHUNK - 1) / CHUNK;  // 342
  // per-layer bases into csr/staging (layer l slice: E_l + n items)
  int cb[4];
  cb[0] = 0;
  for (int i = 1; i < 4; ++i) cb[i] = cb[i - 1] + E_arr[i - 1] + n;

  // workspace carve (bump allocator, 256B aligned)
  char* ws = (char*)d_ws;
  size_t off = 0;
  auto alloc = [&](size_t bytes) -> void* {
    void* p = ws + off;
    off = (off + bytes + 255) & ~(size_t)255;
    return p;
  };
  float*          h      = (float*)alloc((size_t)n * 128 * sizeof(float));
  unsigned short* hb     = (unsigned short*)alloc((size_t)n * 128 * sizeof(unsigned short));
  unsigned short* xlb    = (unsigned short*)alloc((size_t)n * 128 * sizeof(unsigned short));
  unsigned short* xrb    = (unsigned short*)alloc((size_t)n * 128 * sizeof(unsigned short));
  int*            offs4  = (int*)alloc((size_t)4 * (n + 1) * sizeof(int));
  int*            mat    = (int*)alloc((size_t)nchunk * NB * sizeof(int));
  int*            pfx    = (int*)alloc((size_t)nchunk * NB * sizeof(int));
  int*            colsum = (int*)alloc((size_t)NB * sizeof(int));
  int*            colscan= (int*)alloc((size_t)(NB + 1) * sizeof(int));
  int*            staging= (int*)alloc((size_t)nitems * sizeof(int));
  int*            csr4   = (int*)alloc((size_t)nitems * sizeof(int));
  unsigned short* packB  = (unsigned short*)alloc(131072 * sizeof(unsigned short));
  unsigned short* packE  = (unsigned short*)alloc(4096 * sizeof(unsigned short));
  float*          partial= (float*)alloc((size_t)POOLP * 8192 * sizeof(float));
  (void)ws_size; (void)n_in; (void)out_size;

  // dst rows of each edge list
  const int* D[4] = { eptr[0] + E_arr[0], eptr[1] + E_arr[1],
                      eptr[2] + E_arr[2], eptr[3] + E_arr[3] };

  int setup_items = 131072 + 4096 + 4;
  setup_kernel<<<(setup_items + 255) / 256, 256, 0, stream>>>(
      Wl, Wr, embW, packB, packE, offs4, n,
      E_arr[0], E_arr[1], E_arr[2], E_arr[3]);

  const int ntile16 = (n + 15) / 16;
  embed_mfma_kernel<<<(ntile16 + 3) / 4, 256, 0, stream>>>(
      x, packE, embB, hb, n);

  // atomic-free radix-partition CSR build (all 4 graphs)
  hist_kernel<<<nchunk, 256, 0, stream>>>(
      D[0], D[1], D[2], D[3], E_arr[0], E_arr[1], E_arr[2], E_arr[3],
      n, nbk, NB, nitems, mat);
  colscan_a_kernel<<<NB, 256, 0, stream>>>(mat, pfx, nchunk, NB, colsum);
  colscan_b_kernel<<<1, 256, 0, stream>>>(colsum, NB, colscan);
  scatter_kernel<<<nchunk, 256, 0, stream>>>(
      eptr[0], eptr[1], eptr[2], eptr[3], D[0], D[1], D[2], D[3],
      E_arr[0], E_arr[1], E_arr[2], E_arr[3], n, nbk, NB, nitems,
      mat, pfx, colscan, staging);
  finalize_kernel<<<NB, 256, 0, stream>>>(
      staging, colscan, offs4, csr4, n, nbk, cb[0], cb[1], cb[2], cb[3]);

  const int ntile32 = (n + 31) / 32;
  const int gemm_grid = (ntile32 + 1) / 2;          // 2 tiles per block
  for (int l = 0; l < 4; ++l) {
    gemm_mfma_kernel<<<gemm_grid, 256, 0, stream>>>(
        hb, packB + (size_t)l * 32768, xlb, xrb, n);
    gat_dst_kernel<<<((size_t)n * 16 + 255) / 256, 256, 0, stream>>>(
        xlb, xrb, offs4 + (size_t)l * (n + 1), csr4 + cb[l],
        att + (size_t)l * 128, bias + (size_t)l * 128,
        (l == 3) ? h : nullptr, (l < 3) ? hb : nullptr, n);
  }

  pool_partial_kernel<<<POOLP, 256, 0, stream>>>(h, gnode, bidx, partial, ng);
  pool_out_kernel<<<64, 128, 0, stream>>>(partial, outW, outB, (float*)d_out);
}

// Round 15
// 481.454 us; speedup vs baseline: 1.1512x; 1.0261x over previous
//
#include <hip/hip_runtime.h>
#include <cstddef>

// ---------------------------------------------------------------------------
// TransformerNet: 4-layer GATv2 GNN on MI355X (gfx950).
// R15: permuted feature layout. All 128-dim rows (hb/xlb/xrb/h) store dim d
// at position s = 64*(d/64) + (d%16)*4 + (d%64)/16. Under this order the
// MFMA C/D fragment's 4 per-lane values are contiguous -> gemm epilogue is
// 8x 8B stores/lane instead of 32x 2B (R14 disasm: stores were ~1/3 of gemm
// insts); embed same. Perm absorbed in index math: packB rows use d(k), gat
// att/bias via d(pos) (prologue only), pool_out unpermutes via d(k).
// inverse: d(s) = 64*(s/64) + (s%4)*16 + (s%64)/4. Rest identical to R14.
// ---------------------------------------------------------------------------

typedef __attribute__((ext_vector_type(8))) short bf16x8;  // 8 bf16 = 4 VGPR
typedef __attribute__((ext_vector_type(4))) float f32x4;

#define NSH   10              // nodes-per-bucket shift (1024)
#define CHUNK 8192            // items per partition chunk
#define POOLP 256             // pool stage-1 blocks

__device__ __forceinline__ unsigned short f2bf(float f) {
  unsigned int u = __float_as_uint(f);
  u += 0x7fffu + ((u >> 16) & 1u);            // round-to-nearest-even
  return (unsigned short)(u >> 16);
}
__device__ __forceinline__ unsigned short f2bf_rtz(float f) {
  return (unsigned short)(__float_as_uint(f) >> 16);   // truncate (1 inst)
}
// pack two fp32 -> two bf16 (RTZ) in one dword
__device__ __forceinline__ unsigned int pack2bf(float a, float b) {
  return (__float_as_uint(a) >> 16) | (__float_as_uint(b) & 0xFFFF0000u);
}
__device__ __forceinline__ float bf2f(short s) {
  return __uint_as_float(((unsigned int)(unsigned short)s) << 16);
}
// unpack packed pair of bf16 (one uint32) -> float2
__device__ __forceinline__ float2 unpk(unsigned int u) {
  return make_float2(__uint_as_float(u << 16),
                     __uint_as_float(u & 0xFFFF0000u));
}
// storage position s -> logical dim d
__device__ __forceinline__ int dlog(int s) {
  int b = s >> 6, i = s & 63;
  return (b << 6) + ((i & 3) << 4) + (i >> 2);
}

// exclusive scan of a[0..len) in LDS with 256 threads; a rewritten in place;
// returns total. aux = 256-int scratch. len <= 1024.
__device__ __forceinline__ int lds_excl_scan(int* a, int len, int* aux, int tid)
{
  int g = (len + 255) >> 8;                   // elements per thread
  int lo = tid * g;
  int s = 0;
  for (int i = 0; i < g; ++i) { int idx = lo + i; if (idx < len) s += a[idx]; }
  aux[tid] = s;
  __syncthreads();
  for (int d = 1; d < 256; d <<= 1) {
    int v = (tid >= d) ? aux[tid - d] : 0;
    __syncthreads();
    aux[tid] += v;
    __syncthreads();
  }
  int run = aux[tid] - s;                     // exclusive base of this span
  for (int i = 0; i < g; ++i) {
    int idx = lo + i;
    if (idx < len) { int t = a[idx]; a[idx] = run; run += t; }
  }
  int total = aux[255];
  __syncthreads();
  return total;
}

// resolve item id -> (layer, src, dst). Items = all edges then 4*n self-loops.
__device__ __forceinline__ void resolve_item(
    int id, int t1, int t2, int t3, int t4, int n,
    const int* s0, const int* s1, const int* s2, const int* s3,
    const int* d0, const int* d1, const int* d2, const int* d3,
    int& l, int& s, int& d, bool need_src)
{
  if (id < t4) {
    const int *sp, *dp; int e;
    if      (id < t1) { l = 0; e = id;      sp = s0; dp = d0; }
    else if (id < t2) { l = 1; e = id - t1; sp = s1; dp = d1; }
    else if (id < t3) { l = 2; e = id - t2; sp = s2; dp = d2; }
    else              { l = 3; e = id - t3; sp = s3; dp = d3; }
    d = dp[e];
    s = need_src ? sp[e] : 0;
  } else {
    int k = id - t4;
    l = (k >= 3 * n) ? 3 : (k >= 2 * n) ? 2 : (k >= n) ? 1 : 0;
    s = k - l * n; d = s;                     // self-loop
  }
}

// ------- setup: pack layer W + embed W + offs4 layer-end sentinels ---------
// packB[ct=16][kt=4][lane=64][j=8] per layer; element = W[d(kpos)][col],
// kpos = kt*32 + (lane>>4)*8 + j (position in PERMUTED hb row),
// col = ct*16 + (lane&15); ct<8 -> Wl, else Wr.
__global__ __launch_bounds__(256) void setup_kernel(
    const float* __restrict__ Wl, const float* __restrict__ Wr,
    const float* __restrict__ embW,
    unsigned short* __restrict__ packB, unsigned short* __restrict__ packE,
    int* __restrict__ offs4, int n, int e0, int e1, int e2, int e3)
{
  int id = blockIdx.x * 256 + threadIdx.x;
  if (id < 131072) {
    int j    = id & 7;
    int lane = (id >> 3) & 63;
    int kt   = (id >> 9) & 3;
    int ct   = (id >> 11) & 15;
    int l    = id >> 15;
    int kpos = kt * 32 + (lane >> 4) * 8 + j;
    int k    = dlog(kpos);                    // logical W row for this pos
    int col  = ct * 16 + (lane & 15);
    float v = (ct < 8) ? Wl[(size_t)l * 16384 + k * 128 + col]
                       : Wr[(size_t)l * 16384 + k * 128 + (col - 128)];
    packB[id] = f2bf(v);
  }
  int pe = id - 131072;
  if (pe >= 0 && pe < 4096) {
    int j    = pe & 7;
    int lane = (pe >> 3) & 63;
    int ct   = pe >> 9;
    int k    = (lane >> 4) * 8 + j;           // x is not permuted (F_IN=32)
    int col  = ct * 16 + (lane & 15);
    packE[pe] = f2bf(embW[k * 128 + col]);
  }
  int q = pe - 4096;
  if (q >= 0 && q < 4) {
    int El = (q == 0) ? e0 : (q == 1) ? e1 : (q == 2) ? e2 : e3;
    offs4[(size_t)q * (n + 1) + n] = El + n;
  }
}

// ------- embed GEMM (MFMA): hb[n,128](bf16, PERMUTED) = x @ embW + b -------
__global__ __launch_bounds__(256) void embed_mfma_kernel(
    const float* __restrict__ x, const unsigned short* __restrict__ packE,
    const float* __restrict__ b, unsigned short* __restrict__ hb, int n)
{
  const int wave = threadIdx.x >> 6;
  const int lane = threadIdx.x & 63;
  const int rlan = lane & 15;
  const int kgrp = lane >> 4;

  bf16x8 Bf[8];
#pragma unroll
  for (int ct = 0; ct < 8; ++ct)
    Bf[ct] = *(const bf16x8*)(packE + ((size_t)ct * 64 + lane) * 8);
  float bv[8];
#pragma unroll
  for (int ct = 0; ct < 8; ++ct) bv[ct] = b[ct * 16 + rlan];

  const float4* __restrict__ x4 = (const float4*)x;
  const int ntiles = (n + 15) / 16;
  for (int tile = blockIdx.x * 4 + wave; tile < ntiles; tile += gridDim.x * 4) {
    int r = tile * 16 + rlan;
    if (r >= n) r = n - 1;                    // clamp (writes are guarded)
    float4 a0 = x4[(size_t)r * 8 + kgrp * 2];
    float4 a1 = x4[(size_t)r * 8 + kgrp * 2 + 1];
    bf16x8 Af;
    Af[0] = (short)f2bf(a0.x); Af[1] = (short)f2bf(a0.y);
    Af[2] = (short)f2bf(a0.z); Af[3] = (short)f2bf(a0.w);
    Af[4] = (short)f2bf(a1.x); Af[5] = (short)f2bf(a1.y);
    Af[6] = (short)f2bf(a1.z); Af[7] = (short)f2bf(a1.w);

    f32x4 acc[8];
#pragma unroll
    for (int ct = 0; ct < 8; ++ct) {
      acc[ct] = (f32x4){0.f, 0.f, 0.f, 0.f};
      acc[ct] = __builtin_amdgcn_mfma_f32_16x16x32_bf16(Af, Bf[ct], acc[ct], 0, 0, 0);
    }
    // C/D: logical col = ct*16+rlan, row = kgrp*4+reg.
    // permuted store pos for (ct,rlan) = (ct>=4 ? 64:0) + rlan*4 + (ct&3):
    // pack ct 0..3 and 4..7 into two 8B stores per row.
    int rowb = tile * 16 + kgrp * 4;
#pragma unroll
    for (int rr = 0; rr < 4; ++rr) {
      int row = rowb + rr;
      if (row < n) {
        uint2 p0, p1;
        p0.x = pack2bf(acc[0][rr] + bv[0], acc[1][rr] + bv[1]);
        p0.y = pack2bf(acc[2][rr] + bv[2], acc[3][rr] + bv[3]);
        p1.x = pack2bf(acc[4][rr] + bv[4], acc[5][rr] + bv[5]);
        p1.y = pack2bf(acc[6][rr] + bv[6], acc[7][rr] + bv[7]);
        *(uint2*)(hb + (size_t)row * 128 + rlan * 4)      = p0;
        *(uint2*)(hb + (size_t)row * 128 + 64 + rlan * 4) = p1;
      }
    }
  }
}

// ------ layer GEMM (MFMA, LDS-staged A, permuted packed stores) ------------
#define GPAD 136              // padded row stride in shorts (272B)
__global__ __launch_bounds__(256) void gemm_mfma_kernel(
    const unsigned short* __restrict__ hb,
    const unsigned short* __restrict__ packB,   // this layer's [16][4][64][8]
    unsigned short* __restrict__ xlb, unsigned short* __restrict__ xrb, int n)
{
  __shared__ unsigned short hs[32 * GPAD];    // 8.5 KB
  const int tid  = threadIdx.x;
  const int wave = tid >> 6;
  const int lane = tid & 63;
  const int rlan = lane & 15;
  const int kgrp = lane >> 4;

  bf16x8 Bf[4][4];
#pragma unroll
  for (int ct = 0; ct < 4; ++ct)
#pragma unroll
    for (int kt = 0; kt < 4; ++kt)
      Bf[ct][kt] = *(const bf16x8*)(packB +
          ((((size_t)(wave * 4 + ct)) * 4 + kt) * 64 + lane) * 8);

  unsigned short* __restrict__ outp = (wave < 2) ? xlb : xrb;  // wave-uniform
  const int colbase = (wave & 1) * 64;        // permuted block base

  const int ntiles = (n + 31) / 32;
  for (int tile = blockIdx.x; tile < ntiles; tile += gridDim.x) {
    const int row0 = tile * 32;
    __syncthreads();                          // hs safe to overwrite
    // stage 32 rows (8192 shorts) coalesced: 4 x uint4 per thread
#pragma unroll
    for (int i = 0; i < 4; ++i) {
      int g  = (i * 256 + tid) * 8;           // short index within tile
      int r  = g >> 7;                        // row 0..31
      int cc = g & 127;                       // pos 0..120
      int gr = row0 + r; if (gr >= n) gr = n - 1;
      uint4 v = *(const uint4*)(hb + (size_t)gr * 128 + cc);
      *(uint4*)(hs + r * GPAD + cc) = v;
    }
    __syncthreads();

    bf16x8 Af[2][4];
#pragma unroll
    for (int rt = 0; rt < 2; ++rt)
#pragma unroll
      for (int kt = 0; kt < 4; ++kt)
        Af[rt][kt] = *(const bf16x8*)(hs + (rt * 16 + rlan) * GPAD
                                         + kgrp * 8 + kt * 32);

    f32x4 acc[2][4];
#pragma unroll
    for (int rt = 0; rt < 2; ++rt)
#pragma unroll
      for (int ct = 0; ct < 4; ++ct)
        acc[rt][ct] = (f32x4){0.f, 0.f, 0.f, 0.f};
#pragma unroll
    for (int kt = 0; kt < 4; ++kt)
#pragma unroll
      for (int rt = 0; rt < 2; ++rt)
#pragma unroll
        for (int ct = 0; ct < 4; ++ct)
          acc[rt][ct] = __builtin_amdgcn_mfma_f32_16x16x32_bf16(
              Af[rt][kt], Bf[ct][kt], acc[rt][ct], 0, 0, 0);
    // logical col = colbase + ct*16 + rlan -> permuted pos = colbase + rlan*4
    // + ct: the 4 ct values per lane are CONTIGUOUS -> one 8B store per row.
#pragma unroll
    for (int rt = 0; rt < 2; ++rt) {
      int rowb = row0 + rt * 16 + kgrp * 4;
#pragma unroll
      for (int r = 0; r < 4; ++r) {
        int row = rowb + r;
        if (row < n) {
          uint2 pk;
          pk.x = pack2bf(acc[rt][0][r], acc[rt][1][r]);
          pk.y = pack2bf(acc[rt][2][r], acc[rt][3][r]);
          *(uint2*)(outp + (size_t)row * 128 + colbase + rlan * 4) = pk;
        }
      }
    }
  }
}

// ---------------- radix-partition CSR build --------------------------------
__global__ __launch_bounds__(256) void hist_kernel(
    const int* __restrict__ d0, const int* __restrict__ d1,
    const int* __restrict__ d2, const int* __restrict__ d3,
    int e0, int e1, int e2, int e3, int n, int nbk, int NB, int nitems,
    int* __restrict__ mat)
{
  __shared__ int hist[512];
  int tid = threadIdx.x, c = blockIdx.x;
  for (int i = tid; i < NB; i += 256) hist[i] = 0;
  __syncthreads();
  int t1 = e0, t2 = t1 + e1, t3 = t2 + e2, t4 = t3 + e3;
  int base = c * CHUNK;
#pragma unroll
  for (int k = 0; k < CHUNK / 256; ++k) {
    int id = base + k * 256 + tid;
    if (id < nitems) {
      int l, s, d;
      resolve_item(id, t1, t2, t3, t4, n,
                   nullptr, nullptr, nullptr, nullptr, d0, d1, d2, d3,
                   l, s, d, false);
      atomicAdd(&hist[l * nbk + (d >> NSH)], 1);
    }
  }
  __syncthreads();
  for (int i = tid; i < NB; i += 256) mat[(size_t)c * NB + i] = hist[i];
}

__global__ __launch_bounds__(256) void colscan_a_kernel(
    const int* __restrict__ mat, int* __restrict__ pfx,
    int nchunk, int NB, int* __restrict__ colsum)
{
  __shared__ int col[512];
  __shared__ int aux[256];
  int gb = blockIdx.x, tid = threadIdx.x;
  for (int i = tid; i < nchunk; i += 256) col[i] = mat[(size_t)i * NB + gb];
  __syncthreads();
  int tot = lds_excl_scan(col, nchunk, aux, tid);
  for (int i = tid; i < nchunk; i += 256) pfx[(size_t)i * NB + gb] = col[i];
  if (tid == 0) colsum[gb] = tot;
}

__global__ __launch_bounds__(256) void colscan_b_kernel(
    const int* __restrict__ colsum, int NB, int* __restrict__ colscan)
{
  __shared__ int buf[512];
  __shared__ int aux[256];
  int tid = threadIdx.x;
  for (int i = tid; i < NB; i += 256) buf[i] = colsum[i];
  __syncthreads();
  int tot = lds_excl_scan(buf, NB, aux, tid);
  for (int i = tid; i < NB; i += 256) colscan[i] = buf[i];
  if (tid == 0) colscan[NB] = tot;
}

__global__ __launch_bounds__(256) void scatter_kernel(
    const int* __restrict__ s0, const int* __restrict__ s1,
    const int* __restrict__ s2, const int* __restrict__ s3,
    const int* __restrict__ d0, const int* __restrict__ d1,
    const int* __restrict__ d2, const int* __restrict__ d3,
    int e0, int e1, int e2, int e3, int n, int nbk, int NB, int nitems,
    const int* __restrict__ mat, const int* __restrict__ pfx,
    const int* __restrict__ colscan, int* __restrict__ staging)
{
  __shared__ int lbuf[CHUNK];
  __shared__ int hist[512];    // within-chunk exclusive offsets
  __shared__ int cur[512];
  __shared__ int basex[512];
  __shared__ int aux[256];
  int tid = threadIdx.x, c = blockIdx.x;
  for (int i = tid; i < NB; i += 256) hist[i] = mat[(size_t)c * NB + i];
  __syncthreads();
  lds_excl_scan(hist, NB, aux, tid);
  for (int i = tid; i < NB; i += 256) {
    cur[i]   = hist[i];
    basex[i] = colscan[i] + pfx[(size_t)c * NB + i];
  }
  __syncthreads();
  int t1 = e0, t2 = t1 + e1, t3 = t2 + e2, t4 = t3 + e3;
  int base = c * CHUNK;
#pragma unroll
  for (int k = 0; k < CHUNK / 256; ++k) {
    int id = base + k * 256 + tid;
    if (id < nitems) {
      int l, s, d;
      resolve_item(id, t1, t2, t3, t4, n,
                   s0, s1, s2, s3, d0, d1, d2, d3, l, s, d, true);
      int gb = l * nbk + (d >> NSH);
      int p = atomicAdd(&cur[gb], 1);
      lbuf[p] = s | ((d & ((1 << NSH) - 1)) << 17);
    }
  }
  __syncthreads();
  int wave = tid >> 6, lane = tid & 63;
  for (int gb = wave; gb < NB; gb += 4) {
    int st = hist[gb], en = cur[gb];
    int gbase = basex[gb];
    for (int j = lane; j < en - st; j += 64)
      staging[gbase + j] = lbuf[st + j];
  }
}

__global__ __launch_bounds__(256) void finalize_kernel(
    const int* __restrict__ staging, const int* __restrict__ colscan,
    int* __restrict__ offs4, int* __restrict__ csr4, int n, int nbk,
    int cb0, int cb1, int cb2, int cb3)
{
  __shared__ int cnt[1 << NSH];
  __shared__ int pos[1 << NSH];
  __shared__ int aux[256];
  int gb = blockIdx.x, tid = threadIdx.x;
  int l = gb / nbk, b = gb % nbk;
  int beg = colscan[gb], end = colscan[gb + 1];
  int node0 = b << NSH;
  int ncount = n - node0; if (ncount > (1 << NSH)) ncount = 1 << NSH;
  int cbl = (l == 0) ? cb0 : (l == 1) ? cb1 : (l == 2) ? cb2 : cb3;

  for (int i = tid; i < (1 << NSH); i += 256) cnt[i] = 0;
  __syncthreads();
  for (int t = beg + tid; t < end; t += 256)
    atomicAdd(&cnt[staging[t] >> 17], 1);
  __syncthreads();
  lds_excl_scan(cnt, 1 << NSH, aux, tid);
  for (int i = tid; i < (1 << NSH); i += 256) {
    if (i < ncount)
      offs4[(size_t)l * (n + 1) + node0 + i] = beg + cnt[i] - cbl;
    pos[i] = cnt[i];
  }
  __syncthreads();
  for (int t = beg + tid; t < end; t += 256) {
    int e = staging[t];
    int p = atomicAdd(&pos[e >> 17], 1);
    csr4[beg + p] = e & 0x1FFFF;
  }
}

// ---------------- fused GATv2 edge phase (R11 structure) -------------------
// SUBGROUP-PER-NODE; rows are in permuted dim order, so att/bias are indexed
// via dlog(pos) in the prologue (positions themselves stay consistent).
__global__ __launch_bounds__(256) void gat_dst_kernel(
    const unsigned short* __restrict__ xlb,
    const unsigned short* __restrict__ xrb,
    const int* __restrict__ offs, const int* __restrict__ csr,
    const float* __restrict__ att, const float* __restrict__ bias,
    float* __restrict__ hout_f, unsigned short* __restrict__ hout_b, int n)
{
  const float LOG2E = 1.4426950408889634f;
  int wid = (blockIdx.x * 256 + threadIdx.x) >> 4;   // subgroup id = node
  int c   = threadIdx.x & 15;                        // pos chunk c*8..c*8+7
  if (wid >= n) return;

  uint4 xru = *(const uint4*)(xrb + (size_t)wid * 128 + c * 8);
  float2 xr0 = unpk(xru.x), xr1 = unpk(xru.y);
  float2 xr2 = unpk(xru.z), xr3 = unpk(xru.w);
  float av[8], bi[8];
#pragma unroll
  for (int k = 0; k < 8; ++k) {
    int d = dlog(c * 8 + k);
    av[k] = att[d] * LOG2E;
    bi[k] = bias[d];
  }
  float2 a0 = {av[0], av[1]}, a1 = {av[2], av[3]};
  float2 a2 = {av[4], av[5]}, a3 = {av[6], av[7]};

  int beg = offs[wid], end = offs[wid + 1];
  float ssum = 0.f;
  float2 ac0 = {0.f, 0.f}, ac1 = {0.f, 0.f};
  float2 ac2 = {0.f, 0.f}, ac3 = {0.f, 0.f};

  // prologue prefetch (deg >= 1 always)
  int s0 = csr[beg];
  uint4 xu = *(const uint4*)(xlb + (size_t)s0 * 128 + c * 8);

  for (int j = beg; j < end; ++j) {
    uint4 cu = xu;
    int jn = j + 1;
    if (jn < end) {                          // prefetch next (overlaps chain)
      int sn = csr[jn];
      xu = *(const uint4*)(xlb + (size_t)sn * 128 + c * 8);
    }
    float2 xs0 = unpk(cu.x), xs1 = unpk(cu.y);
    float2 xs2 = unpk(cu.z), xs3 = unpk(cu.w);
    float2 t0 = {xs0.x + xr0.x, xs0.y + xr0.y};
    float2 t1 = {xs1.x + xr1.x, xs1.y + xr1.y};
    float2 t2 = {xs2.x + xr2.x, xs2.y + xr2.y};
    float2 t3 = {xs3.x + xr3.x, xs3.y + xr3.y};
    t0.x = fmaxf(t0.x, 0.2f * t0.x); t0.y = fmaxf(t0.y, 0.2f * t0.y);
    t1.x = fmaxf(t1.x, 0.2f * t1.x); t1.y = fmaxf(t1.y, 0.2f * t1.y);
    t2.x = fmaxf(t2.x, 0.2f * t2.x); t2.y = fmaxf(t2.y, 0.2f * t2.y);
    t3.x = fmaxf(t3.x, 0.2f * t3.x); t3.y = fmaxf(t3.y, 0.2f * t3.y);
    float2 pp = {t0.x * a0.x, t0.y * a0.y};
    pp.x = fmaf(t1.x, a1.x, pp.x); pp.y = fmaf(t1.y, a1.y, pp.y);
    pp.x = fmaf(t2.x, a2.x, pp.x); pp.y = fmaf(t2.y, a2.y, pp.y);
    pp.x = fmaf(t3.x, a3.x, pp.x); pp.y = fmaf(t3.y, a3.y, pp.y);
    float part = pp.x + pp.y;
    part += __shfl_xor(part, 1, 64);         // 16-lane group reduction
    part += __shfl_xor(part, 2, 64);
    part += __shfl_xor(part, 4, 64);
    part += __shfl_xor(part, 8, 64);
    float p = __builtin_amdgcn_exp2f(part);  // att pre-scaled by log2e
    ssum += p;
    ac0.x = fmaf(p, xs0.x, ac0.x); ac0.y = fmaf(p, xs0.y, ac0.y);
    ac1.x = fmaf(p, xs1.x, ac1.x); ac1.y = fmaf(p, xs1.y, ac1.y);
    ac2.x = fmaf(p, xs2.x, ac2.x); ac2.y = fmaf(p, xs2.y, ac2.y);
    ac3.x = fmaf(p, xs3.x, ac3.x); ac3.y = fmaf(p, xs3.y, ac3.y);
  }

  float inv = 1.0f / ssum;
  float o[8] = {ac0.x, ac0.y, ac1.x, ac1.y, ac2.x, ac2.y, ac3.x, ac3.y};
#pragma unroll
  for (int k = 0; k < 8; ++k) o[k] = fmaf(o[k], inv, bi[k]);

  if (hout_f) {
    float4 v0 = make_float4(o[0], o[1], o[2], o[3]);
    float4 v1 = make_float4(o[4], o[5], o[6], o[7]);
    *(float4*)(hout_f + (size_t)wid * 128 + c * 8)     = v0;
    *(float4*)(hout_f + (size_t)wid * 128 + c * 8 + 4) = v1;
  } else {
    bf16x8 ob;
#pragma unroll
    for (int k = 0; k < 8; ++k) ob[k] = (short)f2bf(o[k]);
    *(bf16x8*)(hout_b + (size_t)wid * 128 + c * 8) = ob;
  }
}

// ---------------- two-stage pooling + fused reduce+output GEMM -------------
__global__ __launch_bounds__(256) void pool_partial_kernel(
    const float* __restrict__ h, const int* __restrict__ gnode,
    const int* __restrict__ bidx, float* __restrict__ partial, int ng)
{
  __shared__ float acc[64 * 128];           // 32 KiB
  int tid = threadIdx.x;
  for (int t = tid; t < 64 * 128; t += 256) acc[t] = 0.f;
  __syncthreads();
  int col = tid & 127, half = tid >> 7;
  for (int nd = blockIdx.x * 2 + half; nd < ng; nd += gridDim.x * 2) {
    int row = gnode[nd];
    int g   = bidx[nd];
    atomicAdd(&acc[g * 128 + col], h[(size_t)row * 128 + col]);
  }
  __syncthreads();
  float* out = partial + (size_t)blockIdx.x * 8192;
  for (int t = tid; t < 64 * 128; t += 256) out[t] = acc[t];
}

// one block per graph g: reduce partials for row g (permuted dims), then
// out[g] = pooled @ W + b with W rows unpermuted via dlog(k).
__global__ __launch_bounds__(128) void pool_out_kernel(
    const float* __restrict__ partial, const float* __restrict__ W,
    const float* __restrict__ b, float* __restrict__ out)
{
  __shared__ float pr[128];
  int g = blockIdx.x, tid = threadIdx.x;    // tid = pos
  float s = 0.f;
  for (int p = 0; p < POOLP; ++p) s += partial[(size_t)p * 8192 + g * 128 + tid];
  pr[tid] = s;
  __syncthreads();
  if (tid < 16) {
    float acc = b[tid];
#pragma unroll
    for (int k = 0; k < 128; ++k) acc += pr[k] * W[dlog(k) * 16 + tid];
    out[g * 16 + tid] = acc;
  }
}

// ---------------------------------------------------------------------------
extern "C" void kernel_launch(void* const* d_in, const int* in_sizes, int n_in,
                              void* d_out, int out_size, void* d_ws, size_t ws_size,
                              hipStream_t stream)
{
  const float* x    = (const float*)d_in[0];
  const int* ei0    = (const int*)d_in[1];   // edge_index            [2,1e6]
  const int* ei_sg  = (const int*)d_in[2];   // subgraph_edge_index   [2,1e6]
  const int* ei_ns  = (const int*)d_in[3];   // node_subnode_index    [2,2e5]
  const int* ei_sn  = (const int*)d_in[4];   // subnode_node_index    [2,2e5]
  const int* gnode  = (const int*)d_in[5];   // ground_node
  // d_in[6] = subgraph_batch_index (unused by reference)
  const int* bidx   = (const int*)d_in[7];   // batch_idx
  const float* embW = (const float*)d_in[8];
  const float* embB = (const float*)d_in[9];
  const float* Wl   = (const float*)d_in[10];
  const float* Wr   = (const float*)d_in[11];
  const float* att  = (const float*)d_in[12];
  const float* bias = (const float*)d_in[13];
  const float* outW = (const float*)d_in[14];
  const float* outB = (const float*)d_in[15];

  const int n  = in_sizes[0] / 32;           // 100000
  const int ng = in_sizes[5];                // 40000

  // reference layer order: edge_index, node_subnode, subgraph_edge, subnode_node
  const int  E_arr[4] = { in_sizes[1] / 2, in_sizes[3] / 2,
                          in_sizes[2] / 2, in_sizes[4] / 2 };
  const int* eptr[4]  = { ei0, ei_ns, ei_sg, ei_sn };
  const int E_tot  = E_arr[0] + E_arr[1] + E_arr[2] + E_arr[3];
  const int nitems = E_tot + 4 * n;
  const int nbk    = (n + (1 << NSH) - 1) >> NSH;   // buckets per layer (98)
  const int NB     = 4 * nbk;                       // global buckets (392)
  const int nchunk = (nitems + CHUNK - 1) / CHUNK;  // 342
  // per-layer bases into csr/staging (layer l slice: E_l + n items)
  int cb[4];
  cb[0] = 0;
  for (int i = 1; i < 4; ++i) cb[i] = cb[i - 1] + E_arr[i - 1] + n;

  // workspace carve (bump allocator, 256B aligned)
  char* ws = (char*)d_ws;
  size_t off = 0;
  auto alloc = [&](size_t bytes) -> void* {
    void* p = ws + off;
    off = (off + bytes + 255) & ~(size_t)255;
    return p;
  };
  float*          h      = (float*)alloc((size_t)n * 128 * sizeof(float));
  unsigned short* hb     = (unsigned short*)alloc((size_t)n * 128 * sizeof(unsigned short));
  unsigned short* xlb    = (unsigned short*)alloc((size_t)n * 128 * sizeof(unsigned short));
  unsigned short* xrb    = (unsigned short*)alloc((size_t)n * 128 * sizeof(unsigned short));
  int*            offs4  = (int*)alloc((size_t)4 * (n + 1) * sizeof(int));
  int*            mat    = (int*)alloc((size_t)nchunk * NB * sizeof(int));
  int*            pfx    = (int*)alloc((size_t)nchunk * NB * sizeof(int));
  int*            colsum = (int*)alloc((size_t)NB * sizeof(int));
  int*            colscan= (int*)alloc((size_t)(NB + 1) * sizeof(int));
  int*            staging= (int*)alloc((size_t)nitems * sizeof(int));
  int*            csr4   = (int*)alloc((size_t)nitems * sizeof(int));
  unsigned short* packB  = (unsigned short*)alloc(131072 * sizeof(unsigned short));
  unsigned short* packE  = (unsigned short*)alloc(4096 * sizeof(unsigned short));
  float*          partial= (float*)alloc((size_t)POOLP * 8192 * sizeof(float));
  (void)ws_size; (void)n_in; (void)out_size;

  // dst rows of each edge list
  const int* D[4] = { eptr[0] + E_arr[0], eptr[1] + E_arr[1],
                      eptr[2] + E_arr[2], eptr[3] + E_arr[3] };

  int setup_items = 131072 + 4096 + 4;
  setup_kernel<<<(setup_items + 255) / 256, 256, 0, stream>>>(
      Wl, Wr, embW, packB, packE, offs4, n,
      E_arr[0], E_arr[1], E_arr[2], E_arr[3]);

  const int ntile16 = (n + 15) / 16;
  embed_mfma_kernel<<<(ntile16 + 3) / 4, 256, 0, stream>>>(
      x, packE, embB, hb, n);

  // atomic-free radix-partition CSR build (all 4 graphs)
  hist_kernel<<<nchunk, 256, 0, stream>>>(
      D[0], D[1], D[2], D[3], E_arr[0], E_arr[1], E_arr[2], E_arr[3],
      n, nbk, NB, nitems, mat);
  colscan_a_kernel<<<NB, 256, 0, stream>>>(mat, pfx, nchunk, NB, colsum);
  colscan_b_kernel<<<1, 256, 0, stream>>>(colsum, NB, colscan);
  scatter_kernel<<<nchunk, 256, 0, stream>>>(
      eptr[0], eptr[1], eptr[2], eptr[3], D[0], D[1], D[2], D[3],
      E_arr[0], E_arr[1], E_arr[2], E_arr[3], n, nbk, NB, nitems,
      mat, pfx, colscan, staging);
  finalize_kernel<<<NB, 256, 0, stream>>>(
      staging, colscan, offs4, csr4, n, nbk, cb[0], cb[1], cb[2], cb[3]);

  const int ntile32 = (n + 31) / 32;
  const int gemm_grid = (ntile32 + 1) / 2;          // 2 tiles per block
  for (int l = 0; l < 4; ++l) {
    gemm_mfma_kernel<<<gemm_grid, 256, 0, stream>>>(
        hb, packB + (size_t)l * 32768, xlb, xrb, n);
    gat_dst_kernel<<<((size_t)n * 16 + 255) / 256, 256, 0, stream>>>(
        xlb, xrb, offs4 + (size_t)l * (n + 1), csr4 + cb[l],
        att + (size_t)l * 128, bias + (size_t)l * 128,
        (l == 3) ? h : nullptr, (l < 3) ? hb : nullptr, n);
  }

  pool_partial_kernel<<<POOLP, 256, 0, stream>>>(h, gnode, bidx, partial, ng);
  pool_out_kernel<<<64, 128, 0, stream>>>(partial, outW, outB, (float*)d_out);
}

// Round 16
// 481.337 us; speedup vs baseline: 1.1515x; 1.0002x over previous
//
#include <hip/hip_runtime.h>
#include <cstddef>

// ---------------------------------------------------------------------------
// TransformerNet: 4-layer GATv2 GNN on MI355X (gfx950).
// R16: R15 + precomputed PERMUTED att/bias tables (attP pre-scaled by log2e,
// biasP) built in setup. R15's gat prologue computed dlog() per lane + 16
// scalar gathers -> VGPR 32->36, occupancy 60->54%, +3us. Now gat loads
// attP/biasP as straight vectors at pos=c*8: zero perm math in the kernel.
// Everything else identical to R15.
// ---------------------------------------------------------------------------

typedef __attribute__((ext_vector_type(8))) short bf16x8;  // 8 bf16 = 4 VGPR
typedef __attribute__((ext_vector_type(4))) float f32x4;

#define NSH   10              // nodes-per-bucket shift (1024)
#define CHUNK 8192            // items per partition chunk
#define POOLP 256             // pool stage-1 blocks

__device__ __forceinline__ unsigned short f2bf(float f) {
  unsigned int u = __float_as_uint(f);
  u += 0x7fffu + ((u >> 16) & 1u);            // round-to-nearest-even
  return (unsigned short)(u >> 16);
}
// pack two fp32 -> two bf16 (RTZ) in one dword
__device__ __forceinline__ unsigned int pack2bf(float a, float b) {
  return (__float_as_uint(a) >> 16) | (__float_as_uint(b) & 0xFFFF0000u);
}
__device__ __forceinline__ float bf2f(short s) {
  return __uint_as_float(((unsigned int)(unsigned short)s) << 16);
}
// unpack packed pair of bf16 (one uint32) -> float2
__device__ __forceinline__ float2 unpk(unsigned int u) {
  return make_float2(__uint_as_float(u << 16),
                     __uint_as_float(u & 0xFFFF0000u));
}
// storage position s -> logical dim d  (perm: d at pos 64*(d/64)+(d%16)*4+(d%64)/16)
__device__ __forceinline__ int dlog(int s) {
  int b = s >> 6, i = s & 63;
  return (b << 6) + ((i & 3) << 4) + (i >> 2);
}

// exclusive scan of a[0..len) in LDS with 256 threads; a rewritten in place;
// returns total. aux = 256-int scratch. len <= 1024.
__device__ __forceinline__ int lds_excl_scan(int* a, int len, int* aux, int tid)
{
  int g = (len + 255) >> 8;                   // elements per thread
  int lo = tid * g;
  int s = 0;
  for (int i = 0; i < g; ++i) { int idx = lo + i; if (idx < len) s += a[idx]; }
  aux[tid] = s;
  __syncthreads();
  for (int d = 1; d < 256; d <<= 1) {
    int v = (tid >= d) ? aux[tid - d] : 0;
    __syncthreads();
    aux[tid] += v;
    __syncthreads();
  }
  int run = aux[tid] - s;                     // exclusive base of this span
  for (int i = 0; i < g; ++i) {
    int idx = lo + i;
    if (idx < len) { int t = a[idx]; a[idx] = run; run += t; }
  }
  int total = aux[255];
  __syncthreads();
  return total;
}

// resolve item id -> (layer, src, dst). Items = all edges then 4*n self-loops.
__device__ __forceinline__ void resolve_item(
    int id, int t1, int t2, int t3, int t4, int n,
    const int* s0, const int* s1, const int* s2, const int* s3,
    const int* d0, const int* d1, const int* d2, const int* d3,
    int& l, int& s, int& d, bool need_src)
{
  if (id < t4) {
    const int *sp, *dp; int e;
    if      (id < t1) { l = 0; e = id;      sp = s0; dp = d0; }
    else if (id < t2) { l = 1; e = id - t1; sp = s1; dp = d1; }
    else if (id < t3) { l = 2; e = id - t2; sp = s2; dp = d2; }
    else              { l = 3; e = id - t3; sp = s3; dp = d3; }
    d = dp[e];
    s = need_src ? sp[e] : 0;
  } else {
    int k = id - t4;
    l = (k >= 3 * n) ? 3 : (k >= 2 * n) ? 2 : (k >= n) ? 1 : 0;
    s = k - l * n; d = s;                     // self-loop
  }
}

// ------- setup: pack layer W + embed W + permuted att/bias + sentinels -----
// packB[ct=16][kt=4][lane=64][j=8] per layer; element = W[dlog(kpos)][col].
// attP[l][pos] = att[l][dlog(pos)] * log2e;  biasP[l][pos] = bias[l][dlog(pos)].
__global__ __launch_bounds__(256) void setup_kernel(
    const float* __restrict__ Wl, const float* __restrict__ Wr,
    const float* __restrict__ embW,
    const float* __restrict__ att, const float* __restrict__ bias,
    unsigned short* __restrict__ packB, unsigned short* __restrict__ packE,
    float* __restrict__ attP, float* __restrict__ biasP,
    int* __restrict__ offs4, int n, int e0, int e1, int e2, int e3)
{
  const float LOG2E = 1.4426950408889634f;
  int id = blockIdx.x * 256 + threadIdx.x;
  if (id < 131072) {
    int j    = id & 7;
    int lane = (id >> 3) & 63;
    int kt   = (id >> 9) & 3;
    int ct   = (id >> 11) & 15;
    int l    = id >> 15;
    int kpos = kt * 32 + (lane >> 4) * 8 + j;
    int k    = dlog(kpos);                    // logical W row for this pos
    int col  = ct * 16 + (lane & 15);
    float v = (ct < 8) ? Wl[(size_t)l * 16384 + k * 128 + col]
                       : Wr[(size_t)l * 16384 + k * 128 + (col - 128)];
    packB[id] = f2bf(v);
  }
  int pe = id - 131072;
  if (pe >= 0 && pe < 4096) {
    int j    = pe & 7;
    int lane = (pe >> 3) & 63;
    int ct   = pe >> 9;
    int k    = (lane >> 4) * 8 + j;           // x is not permuted (F_IN=32)
    int col  = ct * 16 + (lane & 15);
    packE[pe] = f2bf(embW[k * 128 + col]);
  }
  int ab = pe - 4096;
  if (ab >= 0 && ab < 512) {                  // 4 layers x 128 positions
    int l = ab >> 7, pos = ab & 127;
    int d = dlog(pos);
    attP[ab]  = att[l * 128 + d] * LOG2E;
    biasP[ab] = bias[l * 128 + d];
  }
  int q = ab - 512;
  if (q >= 0 && q < 4) {
    int El = (q == 0) ? e0 : (q == 1) ? e1 : (q == 2) ? e2 : e3;
    offs4[(size_t)q * (n + 1) + n] = El + n;
  }
}

// ------- embed GEMM (MFMA): hb[n,128](bf16, PERMUTED) = x @ embW + b -------
__global__ __launch_bounds__(256) void embed_mfma_kernel(
    const float* __restrict__ x, const unsigned short* __restrict__ packE,
    const float* __restrict__ b, unsigned short* __restrict__ hb, int n)
{
  const int wave = threadIdx.x >> 6;
  const int lane = threadIdx.x & 63;
  const int rlan = lane & 15;
  const int kgrp = lane >> 4;

  bf16x8 Bf[8];
#pragma unroll
  for (int ct = 0; ct < 8; ++ct)
    Bf[ct] = *(const bf16x8*)(packE + ((size_t)ct * 64 + lane) * 8);
  float bv[8];
#pragma unroll
  for (int ct = 0; ct < 8; ++ct) bv[ct] = b[ct * 16 + rlan];

  const float4* __restrict__ x4 = (const float4*)x;
  const int ntiles = (n + 15) / 16;
  for (int tile = blockIdx.x * 4 + wave; tile < ntiles; tile += gridDim.x * 4) {
    int r = tile * 16 + rlan;
    if (r >= n) r = n - 1;                    // clamp (writes are guarded)
    float4 a0 = x4[(size_t)r * 8 + kgrp * 2];
    float4 a1 = x4[(size_t)r * 8 + kgrp * 2 + 1];
    bf16x8 Af;
    Af[0] = (short)f2bf(a0.x); Af[1] = (short)f2bf(a0.y);
    Af[2] = (short)f2bf(a0.z); Af[3] = (short)f2bf(a0.w);
    Af[4] = (short)f2bf(a1.x); Af[5] = (short)f2bf(a1.y);
    Af[6] = (short)f2bf(a1.z); Af[7] = (short)f2bf(a1.w);

    f32x4 acc[8];
#pragma unroll
    for (int ct = 0; ct < 8; ++ct) {
      acc[ct] = (f32x4){0.f, 0.f, 0.f, 0.f};
      acc[ct] = __builtin_amdgcn_mfma_f32_16x16x32_bf16(Af, Bf[ct], acc[ct], 0, 0, 0);
    }
    // permuted store pos for (ct,rlan) = (ct>=4 ? 64:0) + rlan*4 + (ct&3)
    int rowb = tile * 16 + kgrp * 4;
#pragma unroll
    for (int rr = 0; rr < 4; ++rr) {
      int row = rowb + rr;
      if (row < n) {
        uint2 p0, p1;
        p0.x = pack2bf(acc[0][rr] + bv[0], acc[1][rr] + bv[1]);
        p0.y = pack2bf(acc[2][rr] + bv[2], acc[3][rr] + bv[3]);
        p1.x = pack2bf(acc[4][rr] + bv[4], acc[5][rr] + bv[5]);
        p1.y = pack2bf(acc[6][rr] + bv[6], acc[7][rr] + bv[7]);
        *(uint2*)(hb + (size_t)row * 128 + rlan * 4)      = p0;
        *(uint2*)(hb + (size_t)row * 128 + 64 + rlan * 4) = p1;
      }
    }
  }
}

// ------ layer GEMM (MFMA, LDS-staged A, permuted packed stores) ------------
#define GPAD 136              // padded row stride in shorts (272B)
__global__ __launch_bounds__(256) void gemm_mfma_kernel(
    const unsigned short* __restrict__ hb,
    const unsigned short* __restrict__ packB,   // this layer's [16][4][64][8]
    unsigned short* __restrict__ xlb, unsigned short* __restrict__ xrb, int n)
{
  __shared__ unsigned short hs[32 * GPAD];    // 8.5 KB
  const int tid  = threadIdx.x;
  const int wave = tid >> 6;
  const int lane = tid & 63;
  const int rlan = lane & 15;
  const int kgrp = lane >> 4;

  bf16x8 Bf[4][4];
#pragma unroll
  for (int ct = 0; ct < 4; ++ct)
#pragma unroll
    for (int kt = 0; kt < 4; ++kt)
      Bf[ct][kt] = *(const bf16x8*)(packB +
          ((((size_t)(wave * 4 + ct)) * 4 + kt) * 64 + lane) * 8);

  unsigned short* __restrict__ outp = (wave < 2) ? xlb : xrb;  // wave-uniform
  const int colbase = (wave & 1) * 64;        // permuted block base

  const int ntiles = (n + 31) / 32;
  for (int tile = blockIdx.x; tile < ntiles; tile += gridDim.x) {
    const int row0 = tile * 32;
    __syncthreads();                          // hs safe to overwrite
    // stage 32 rows (8192 shorts) coalesced: 4 x uint4 per thread
#pragma unroll
    for (int i = 0; i < 4; ++i) {
      int g  = (i * 256 + tid) * 8;           // short index within tile
      int r  = g >> 7;                        // row 0..31
      int cc = g & 127;                       // pos 0..120
      int gr = row0 + r; if (gr >= n) gr = n - 1;
      uint4 v = *(const uint4*)(hb + (size_t)gr * 128 + cc);
      *(uint4*)(hs + r * GPAD + cc) = v;
    }
    __syncthreads();

    bf16x8 Af[2][4];
#pragma unroll
    for (int rt = 0; rt < 2; ++rt)
#pragma unroll
      for (int kt = 0; kt < 4; ++kt)
        Af[rt][kt] = *(const bf16x8*)(hs + (rt * 16 + rlan) * GPAD
                                         + kgrp * 8 + kt * 32);

    f32x4 acc[2][4];
#pragma unroll
    for (int rt = 0; rt < 2; ++rt)
#pragma unroll
      for (int ct = 0; ct < 4; ++ct)
        acc[rt][ct] = (f32x4){0.f, 0.f, 0.f, 0.f};
#pragma unroll
    for (int kt = 0; kt < 4; ++kt)
#pragma unroll
      for (int rt = 0; rt < 2; ++rt)
#pragma unroll
        for (int ct = 0; ct < 4; ++ct)
          acc[rt][ct] = __builtin_amdgcn_mfma_f32_16x16x32_bf16(
              Af[rt][kt], Bf[ct][kt], acc[rt][ct], 0, 0, 0);
    // permuted pos = colbase + rlan*4 + ct -> 4 ct values contiguous: 8B store
#pragma unroll
    for (int rt = 0; rt < 2; ++rt) {
      int rowb = row0 + rt * 16 + kgrp * 4;
#pragma unroll
      for (int r = 0; r < 4; ++r) {
        int row = rowb + r;
        if (row < n) {
          uint2 pk;
          pk.x = pack2bf(acc[rt][0][r], acc[rt][1][r]);
          pk.y = pack2bf(acc[rt][2][r], acc[rt][3][r]);
          *(uint2*)(outp + (size_t)row * 128 + colbase + rlan * 4) = pk;
        }
      }
    }
  }
}

// ---------------- radix-partition CSR build --------------------------------
__global__ __launch_bounds__(256) void hist_kernel(
    const int* __restrict__ d0, const int* __restrict__ d1,
    const int* __restrict__ d2, const int* __restrict__ d3,
    int e0, int e1, int e2, int e3, int n, int nbk, int NB, int nitems,
    int* __restrict__ mat)
{
  __shared__ int hist[512];
  int tid = threadIdx.x, c = blockIdx.x;
  for (int i = tid; i < NB; i += 256) hist[i] = 0;
  __syncthreads();
  int t1 = e0, t2 = t1 + e1, t3 = t2 + e2, t4 = t3 + e3;
  int base = c * CHUNK;
#pragma unroll
  for (int k = 0; k < CHUNK / 256; ++k) {
    int id = base + k * 256 + tid;
    if (id < nitems) {
      int l, s, d;
      resolve_item(id, t1, t2, t3, t4, n,
                   nullptr, nullptr, nullptr, nullptr, d0, d1, d2, d3,
                   l, s, d, false);
      atomicAdd(&hist[l * nbk + (d >> NSH)], 1);
    }
  }
  __syncthreads();
  for (int i = tid; i < NB; i += 256) mat[(size_t)c * NB + i] = hist[i];
}

__global__ __launch_bounds__(256) void colscan_a_kernel(
    const int* __restrict__ mat, int* __restrict__ pfx,
    int nchunk, int NB, int* __restrict__ colsum)
{
  __shared__ int col[512];
  __shared__ int aux[256];
  int gb = blockIdx.x, tid = threadIdx.x;
  for (int i = tid; i < nchunk; i += 256) col[i] = mat[(size_t)i * NB + gb];
  __syncthreads();
  int tot = lds_excl_scan(col, nchunk, aux, tid);
  for (int i = tid; i < nchunk; i += 256) pfx[(size_t)i * NB + gb] = col[i];
  if (tid == 0) colsum[gb] = tot;
}

__global__ __launch_bounds__(256) void colscan_b_kernel(
    const int* __restrict__ colsum, int NB, int* __restrict__ colscan)
{
  __shared__ int buf[512];
  __shared__ int aux[256];
  int tid = threadIdx.x;
  for (int i = tid; i < NB; i += 256) buf[i] = colsum[i];
  __syncthreads();
  int tot = lds_excl_scan(buf, NB, aux, tid);
  for (int i = tid; i < NB; i += 256) colscan[i] = buf[i];
  if (tid == 0) colscan[NB] = tot;
}

__global__ __launch_bounds__(256) void scatter_kernel(
    const int* __restrict__ s0, const int* __restrict__ s1,
    const int* __restrict__ s2, const int* __restrict__ s3,
    const int* __restrict__ d0, const int* __restrict__ d1,
    const int* __restrict__ d2, const int* __restrict__ d3,
    int e0, int e1, int e2, int e3, int n, int nbk, int NB, int nitems,
    const int* __restrict__ mat, const int* __restrict__ pfx,
    const int* __restrict__ colscan, int* __restrict__ staging)
{
  __shared__ int lbuf[CHUNK];
  __shared__ int hist[512];    // within-chunk exclusive offsets
  __shared__ int cur[512];
  __shared__ int basex[512];
  __shared__ int aux[256];
  int tid = threadIdx.x, c = blockIdx.x;
  for (int i = tid; i < NB; i += 256) hist[i] = mat[(size_t)c * NB + i];
  __syncthreads();
  lds_excl_scan(hist, NB, aux, tid);
  for (int i = tid; i < NB; i += 256) {
    cur[i]   = hist[i];
    basex[i] = colscan[i] + pfx[(size_t)c * NB + i];
  }
  __syncthreads();
  int t1 = e0, t2 = t1 + e1, t3 = t2 + e2, t4 = t3 + e3;
  int base = c * CHUNK;
#pragma unroll
  for (int k = 0; k < CHUNK / 256; ++k) {
    int id = base + k * 256 + tid;
    if (id < nitems) {
      int l, s, d;
      resolve_item(id, t1, t2, t3, t4, n,
                   s0, s1, s2, s3, d0, d1, d2, d3, l, s, d, true);
      int gb = l * nbk + (d >> NSH);
      int p = atomicAdd(&cur[gb], 1);
      lbuf[p] = s | ((d & ((1 << NSH) - 1)) << 17);
    }
  }
  __syncthreads();
  int wave = tid >> 6, lane = tid & 63;
  for (int gb = wave; gb < NB; gb += 4) {
    int st = hist[gb], en = cur[gb];
    int gbase = basex[gb];
    for (int j = lane; j < en - st; j += 64)
      staging[gbase + j] = lbuf[st + j];
  }
}

__global__ __launch_bounds__(256) void finalize_kernel(
    const int* __restrict__ staging, const int* __restrict__ colscan,
    int* __restrict__ offs4, int* __restrict__ csr4, int n, int nbk,
    int cb0, int cb1, int cb2, int cb3)
{
  __shared__ int cnt[1 << NSH];
  __shared__ int pos[1 << NSH];
  __shared__ int aux[256];
  int gb = blockIdx.x, tid = threadIdx.x;
  int l = gb / nbk, b = gb % nbk;
  int beg = colscan[gb], end = colscan[gb + 1];
  int node0 = b << NSH;
  int ncount = n - node0; if (ncount > (1 << NSH)) ncount = 1 << NSH;
  int cbl = (l == 0) ? cb0 : (l == 1) ? cb1 : (l == 2) ? cb2 : cb3;

  for (int i = tid; i < (1 << NSH); i += 256) cnt[i] = 0;
  __syncthreads();
  for (int t = beg + tid; t < end; t += 256)
    atomicAdd(&cnt[staging[t] >> 17], 1);
  __syncthreads();
  lds_excl_scan(cnt, 1 << NSH, aux, tid);
  for (int i = tid; i < (1 << NSH); i += 256) {
    if (i < ncount)
      offs4[(size_t)l * (n + 1) + node0 + i] = beg + cnt[i] - cbl;
    pos[i] = cnt[i];
  }
  __syncthreads();
  for (int t = beg + tid; t < end; t += 256) {
    int e = staging[t];
    int p = atomicAdd(&pos[e >> 17], 1);
    csr4[beg + p] = e & 0x1FFFF;
  }
}

// ---------------- fused GATv2 edge phase (R11 structure) -------------------
// SUBGROUP-PER-NODE; attP/biasP are already in permuted order + log2e-scaled.
__global__ __launch_bounds__(256) void gat_dst_kernel(
    const unsigned short* __restrict__ xlb,
    const unsigned short* __restrict__ xrb,
    const int* __restrict__ offs, const int* __restrict__ csr,
    const float* __restrict__ attP, const float* __restrict__ biasP,
    float* __restrict__ hout_f, unsigned short* __restrict__ hout_b, int n)
{
  int wid = (blockIdx.x * 256 + threadIdx.x) >> 4;   // subgroup id = node
  int c   = threadIdx.x & 15;                        // pos chunk c*8..c*8+7
  if (wid >= n) return;

  uint4 xru = *(const uint4*)(xrb + (size_t)wid * 128 + c * 8);
  float2 xr0 = unpk(xru.x), xr1 = unpk(xru.y);
  float2 xr2 = unpk(xru.z), xr3 = unpk(xru.w);
  const float2* att2 = (const float2*)(attP + c * 8);
  float2 a0 = att2[0], a1 = att2[1], a2 = att2[2], a3 = att2[3];

  int beg = offs[wid], end = offs[wid + 1];
  float ssum = 0.f;
  float2 ac0 = {0.f, 0.f}, ac1 = {0.f, 0.f};
  float2 ac2 = {0.f, 0.f}, ac3 = {0.f, 0.f};

  // prologue prefetch (deg >= 1 always)
  int s0 = csr[beg];
  uint4 xu = *(const uint4*)(xlb + (size_t)s0 * 128 + c * 8);

  for (int j = beg; j < end; ++j) {
    uint4 cu = xu;
    int jn = j + 1;
    if (jn < end) {                          // prefetch next (overlaps chain)
      int sn = csr[jn];
      xu = *(const uint4*)(xlb + (size_t)sn * 128 + c * 8);
    }
    float2 xs0 = unpk(cu.x), xs1 = unpk(cu.y);
    float2 xs2 = unpk(cu.z), xs3 = unpk(cu.w);
    float2 t0 = {xs0.x + xr0.x, xs0.y + xr0.y};
    float2 t1 = {xs1.x + xr1.x, xs1.y + xr1.y};
    float2 t2 = {xs2.x + xr2.x, xs2.y + xr2.y};
    float2 t3 = {xs3.x + xr3.x, xs3.y + xr3.y};
    t0.x = fmaxf(t0.x, 0.2f * t0.x); t0.y = fmaxf(t0.y, 0.2f * t0.y);
    t1.x = fmaxf(t1.x, 0.2f * t1.x); t1.y = fmaxf(t1.y, 0.2f * t1.y);
    t2.x = fmaxf(t2.x, 0.2f * t2.x); t2.y = fmaxf(t2.y, 0.2f * t2.y);
    t3.x = fmaxf(t3.x, 0.2f * t3.x); t3.y = fmaxf(t3.y, 0.2f * t3.y);
    float2 pp = {t0.x * a0.x, t0.y * a0.y};
    pp.x = fmaf(t1.x, a1.x, pp.x); pp.y = fmaf(t1.y, a1.y, pp.y);
    pp.x = fmaf(t2.x, a2.x, pp.x); pp.y = fmaf(t2.y, a2.y, pp.y);
    pp.x = fmaf(t3.x, a3.x, pp.x); pp.y = fmaf(t3.y, a3.y, pp.y);
    float part = pp.x + pp.y;
    part += __shfl_xor(part, 1, 64);         // 16-lane group reduction
    part += __shfl_xor(part, 2, 64);
    part += __shfl_xor(part, 4, 64);
    part += __shfl_xor(part, 8, 64);
    float p = __builtin_amdgcn_exp2f(part);  // attP pre-scaled by log2e
    ssum += p;
    ac0.x = fmaf(p, xs0.x, ac0.x); ac0.y = fmaf(p, xs0.y, ac0.y);
    ac1.x = fmaf(p, xs1.x, ac1.x); ac1.y = fmaf(p, xs1.y, ac1.y);
    ac2.x = fmaf(p, xs2.x, ac2.x); ac2.y = fmaf(p, xs2.y, ac2.y);
    ac3.x = fmaf(p, xs3.x, ac3.x); ac3.y = fmaf(p, xs3.y, ac3.y);
  }

  float inv = 1.0f / ssum;
  float o[8] = {ac0.x, ac0.y, ac1.x, ac1.y, ac2.x, ac2.y, ac3.x, ac3.y};
  const float* bi = biasP + c * 8;
#pragma unroll
  for (int k = 0; k < 8; ++k) o[k] = fmaf(o[k], inv, bi[k]);

  if (hout_f) {
    float4 v0 = make_float4(o[0], o[1], o[2], o[3]);
    float4 v1 = make_float4(o[4], o[5], o[6], o[7]);
    *(float4*)(hout_f + (size_t)wid * 128 + c * 8)     = v0;
    *(float4*)(hout_f + (size_t)wid * 128 + c * 8 + 4) = v1;
  } else {
    bf16x8 ob;
#pragma unroll
    for (int k = 0; k < 8; ++k) ob[k] = (short)f2bf(o[k]);
    *(bf16x8*)(hout_b + (size_t)wid * 128 + c * 8) = ob;
  }
}

// ---------------- two-stage pooling + fused reduce+output GEMM -------------
__global__ __launch_bounds__(256) void pool_partial_kernel(
    const float* __restrict__ h, const int* __restrict__ gnode,
    const int* __restrict__ bidx, float* __restrict__ partial, int ng)
{
  __shared__ float acc[64 * 128];           // 32 KiB
  int tid = threadIdx.x;
  for (int t = tid; t < 64 * 128; t += 256) acc[t] = 0.f;
  __syncthreads();
  int col = tid & 127, half = tid >> 7;
  for (int nd = blockIdx.x * 2 + half; nd < ng; nd += gridDim.x * 2) {
    int row = gnode[nd];
    int g   = bidx[nd];
    atomicAdd(&acc[g * 128 + col], h[(size_t)row * 128 + col]);
  }
  __syncthreads();
  float* out = partial + (size_t)blockIdx.x * 8192;
  for (int t = tid; t < 64 * 128; t += 256) out[t] = acc[t];
}

// one block per graph g: reduce partials for row g (permuted dims), then
// out[g] = pooled @ W + b with W rows unpermuted via dlog(k).
__global__ __launch_bounds__(128) void pool_out_kernel(
    const float* __restrict__ partial, const float* __restrict__ W,
    const float* __restrict__ b, float* __restrict__ out)
{
  __shared__ float pr[128];
  int g = blockIdx.x, tid = threadIdx.x;    // tid = pos
  float s = 0.f;
  for (int p = 0; p < POOLP; ++p) s += partial[(size_t)p * 8192 + g * 128 + tid];
  pr[tid] = s;
  __syncthreads();
  if (tid < 16) {
    float acc = b[tid];
#pragma unroll
    for (int k = 0; k < 128; ++k) acc += pr[k] * W[dlog(k) * 16 + tid];
    out[g * 16 + tid] = acc;
  }
}

// ---------------------------------------------------------------------------
extern "C" void kernel_launch(void* const* d_in, const int* in_sizes, int n_in,
                              void* d_out, int out_size, void* d_ws, size_t ws_size,
                              hipStream_t stream)
{
  const float* x    = (const float*)d_in[0];
  const int* ei0    = (const int*)d_in[1];   // edge_index            [2,1e6]
  const int* ei_sg  = (const int*)d_in[2];   // subgraph_edge_index   [2,1e6]
  const int* ei_ns  = (const int*)d_in[3];   // node_subnode_index    [2,2e5]
  const int* ei_sn  = (const int*)d_in[4];   // subnode_node_index    [2,2e5]
  const int* gnode  = (const int*)d_in[5];   // ground_node
  // d_in[6] = subgraph_batch_index (unused by reference)
  const int* bidx   = (const int*)d_in[7];   // batch_idx
  const float* embW = (const float*)d_in[8];
  const float* embB = (const float*)d_in[9];
  const float* Wl   = (const float*)d_in[10];
  const float* Wr   = (const float*)d_in[11];
  const float* att  = (const float*)d_in[12];
  const float* bias = (const float*)d_in[13];
  const float* outW = (const float*)d_in[14];
  const float* outB = (const float*)d_in[15];

  const int n  = in_sizes[0] / 32;           // 100000
  const int ng = in_sizes[5];                // 40000

  // reference layer order: edge_index, node_subnode, subgraph_edge, subnode_node
  const int  E_arr[4] = { in_sizes[1] / 2, in_sizes[3] / 2,
                          in_sizes[2] / 2, in_sizes[4] / 2 };
  const int* eptr[4]  = { ei0, ei_ns, ei_sg, ei_sn };
  const int E_tot  = E_arr[0] + E_arr[1] + E_arr[2] + E_arr[3];
  const int nitems = E_tot + 4 * n;
  const int nbk    = (n + (1 << NSH) - 1) >> NSH;   // buckets per layer (98)
  const int NB     = 4 * nbk;                       // global buckets (392)
  const int nchunk = (nitems + CHUNK - 1) / CHUNK;  // 342
  // per-layer bases into csr/staging (layer l slice: E_l + n items)
  int cb[4];
  cb[0] = 0;
  for (int i = 1; i < 4; ++i) cb[i] = cb[i - 1] + E_arr[i - 1] + n;

  // workspace carve (bump allocator, 256B aligned)
  char* ws = (char*)d_ws;
  size_t off = 0;
  auto alloc = [&](size_t bytes) -> void* {
    void* p = ws + off;
    off = (off + bytes + 255) & ~(size_t)255;
    return p;
  };
  float*          h      = (float*)alloc((size_t)n * 128 * sizeof(float));
  unsigned short* hb     = (unsigned short*)alloc((size_t)n * 128 * sizeof(unsigned short));
  unsigned short* xlb    = (unsigned short*)alloc((size_t)n * 128 * sizeof(unsigned short));
  unsigned short* xrb    = (unsigned short*)alloc((size_t)n * 128 * sizeof(unsigned short));
  int*            offs4  = (int*)alloc((size_t)4 * (n + 1) * sizeof(int));
  int*            mat    = (int*)alloc((size_t)nchunk * NB * sizeof(int));
  int*            pfx    = (int*)alloc((size_t)nchunk * NB * sizeof(int));
  int*            colsum = (int*)alloc((size_t)NB * sizeof(int));
  int*            colscan= (int*)alloc((size_t)(NB + 1) * sizeof(int));
  int*            staging= (int*)alloc((size_t)nitems * sizeof(int));
  int*            csr4   = (int*)alloc((size_t)nitems * sizeof(int));
  unsigned short* packB  = (unsigned short*)alloc(131072 * sizeof(unsigned short));
  unsigned short* packE  = (unsigned short*)alloc(4096 * sizeof(unsigned short));
  float*          attP   = (float*)alloc(512 * sizeof(float));
  float*          biasP  = (float*)alloc(512 * sizeof(float));
  float*          partial= (float*)alloc((size_t)POOLP * 8192 * sizeof(float));
  (void)ws_size; (void)n_in; (void)out_size;

  // dst rows of each edge list
  const int* D[4] = { eptr[0] + E_arr[0], eptr[1] + E_arr[1],
                      eptr[2] + E_arr[2], eptr[3] + E_arr[3] };

  int setup_items = 131072 + 4096 + 512 + 4;
  setup_kernel<<<(setup_items + 255) / 256, 256, 0, stream>>>(
      Wl, Wr, embW, att, bias, packB, packE, attP, biasP, offs4, n,
      E_arr[0], E_arr[1], E_arr[2], E_arr[3]);

  const int ntile16 = (n + 15) / 16;
  embed_mfma_kernel<<<(ntile16 + 3) / 4, 256, 0, stream>>>(
      x, packE, embB, hb, n);

  // atomic-free radix-partition CSR build (all 4 graphs)
  hist_kernel<<<nchunk, 256, 0, stream>>>(
      D[0], D[1], D[2], D[3], E_arr[0], E_arr[1], E_arr[2], E_arr[3],
      n, nbk, NB, nitems, mat);
  colscan_a_kernel<<<NB, 256, 0, stream>>>(mat, pfx, nchunk, NB, colsum);
  colscan_b_kernel<<<1, 256, 0, stream>>>(colsum, NB, colscan);
  scatter_kernel<<<nchunk, 256, 0, stream>>>(
      eptr[0], eptr[1], eptr[2], eptr[3], D[0], D[1], D[2], D[3],
      E_arr[0], E_arr[1], E_arr[2], E_arr[3], n, nbk, NB, nitems,
      mat, pfx, colscan, staging);
  finalize_kernel<<<NB, 256, 0, stream>>>(
      staging, colscan, offs4, csr4, n, nbk, cb[0], cb[1], cb[2], cb[3]);

  const int ntile32 = (n + 31) / 32;
  const int gemm_grid = (ntile32 + 1) / 2;          // 2 tiles per block
  for (int l = 0; l < 4; ++l) {
    gemm_mfma_kernel<<<gemm_grid, 256, 0, stream>>>(
        hb, packB + (size_t)l * 32768, xlb, xrb, n);
    gat_dst_kernel<<<((size_t)n * 16 + 255) / 256, 256, 0, stream>>>(
        xlb, xrb, offs4 + (size_t)l * (n + 1), csr4 + cb[l],
        attP + l * 128, biasP + l * 128,
        (l == 3) ? h : nullptr, (l < 3) ? hb : nullptr, n);
  }

  pool_partial_kernel<<<POOLP, 256, 0, stream>>>(h, gnode, bidx, partial, ng);
  pool_out_kernel<<<64, 128, 0, stream>>>(partial, outW, outB, (float*)d_out);
}